// Round 1
// baseline (2276.940 us; speedup 1.0000x reference)
//
#include <hip/hip_runtime.h>
#include <math.h>

#define HEADS 16
#define DH 64
#define NB 4
#define SEQ 4096
#define DIM 1024
#define ROWS (NB * SEQ)
#define SCALE 0.125f

typedef float4 f4;

__device__ __forceinline__ float elu1(float v) {
  // elu(x)+1 : x>0 ? x+1 : exp(x)
  return v > 0.f ? v + 1.f : __expf(v);
}

// ---------------------------------------------------------------------------
// K1: fused k,v projection (per-head 64-col slice) + kv / ksum partial reduce
// grid(nsplit, 64) block(256); each block: SEQ/nsplit rows in 128-row subtiles
// ---------------------------------------------------------------------------
__global__ __launch_bounds__(256) void k1_kv(
    const float* __restrict__ x, const float* __restrict__ Wk,
    const float* __restrict__ Wv, float* __restrict__ kv_part,
    float* __restrict__ ksum_part, int nsplit) {
  const int split = blockIdx.x;
  const int bh = blockIdx.y;
  const int b = bh >> 4, h = bh & 15;
  const int t = (int)threadIdx.x;
  const int tr = t >> 4, tc = t & 15;

  __shared__ float smem[2 * 128 * 64];        // 64 KiB
  float* xs  = smem;                          // [128][33]   (gemm stage)
  float* wks = smem + 128 * 33;               // [32][64]
  float* wvs = wks + 32 * 64;                 // [32][64]
  float* kl  = smem;                          // [128][64]   (kv stage, aliases)
  float* vl  = smem + 128 * 64;               // [128][64]

  float kvacc[4][4] = {{0.f}};
  float ksacc = 0.f;

  const int rows_per_block = SEQ / nsplit;
  const int nsub = rows_per_block >> 7;

  for (int st = 0; st < nsub; ++st) {
    const int row0 = b * SEQ + split * rows_per_block + st * 128;
    float ak[8][4] = {{0.f}}, av[8][4] = {{0.f}};

    for (int k0 = 0; k0 < DIM; k0 += 32) {
      __syncthreads();  // protect prev-stage reads of aliased smem
      // x tile 128x32 (coalesced float4, scalar LDS store due to pad-33)
#pragma unroll
      for (int it = 0; it < 4; ++it) {
        const int r = (t >> 3) + 32 * it;
        const int c = (t & 7) << 2;
        const f4 xv = *reinterpret_cast<const f4*>(
            x + (size_t)(row0 + r) * DIM + k0 + c);
        float* d = xs + r * 33 + c;
        d[0] = xv.x; d[1] = xv.y; d[2] = xv.z; d[3] = xv.w;
      }
      // W tiles 32x64 for this head's column slice
#pragma unroll
      for (int it = 0; it < 2; ++it) {
        const int r = (t >> 4) + 16 * it;
        const int c = (t & 15) << 2;
        const size_t g = (size_t)(k0 + r) * DIM + h * DH + c;
        *reinterpret_cast<f4*>(wks + r * 64 + c) =
            *reinterpret_cast<const f4*>(Wk + g);
        *reinterpret_cast<f4*>(wvs + r * 64 + c) =
            *reinterpret_cast<const f4*>(Wv + g);
      }
      __syncthreads();
#pragma unroll
      for (int kk = 0; kk < 32; ++kk) {
        float xr[8];
#pragma unroll
        for (int i = 0; i < 8; ++i) xr[i] = xs[(tr + 16 * i) * 33 + kk];
        const f4 wk4 = *reinterpret_cast<const f4*>(&wks[kk * 64 + (tc << 2)]);
        const f4 wv4 = *reinterpret_cast<const f4*>(&wvs[kk * 64 + (tc << 2)]);
#pragma unroll
        for (int i = 0; i < 8; ++i) {
          ak[i][0] = fmaf(xr[i], wk4.x, ak[i][0]);
          ak[i][1] = fmaf(xr[i], wk4.y, ak[i][1]);
          ak[i][2] = fmaf(xr[i], wk4.z, ak[i][2]);
          ak[i][3] = fmaf(xr[i], wk4.w, ak[i][3]);
          av[i][0] = fmaf(xr[i], wv4.x, av[i][0]);
          av[i][1] = fmaf(xr[i], wv4.y, av[i][1]);
          av[i][2] = fmaf(xr[i], wv4.z, av[i][2]);
          av[i][3] = fmaf(xr[i], wv4.w, av[i][3]);
        }
      }
    }
    __syncthreads();  // done with xs/w tiles; write k,v tiles (aliased region)
#pragma unroll
    for (int i = 0; i < 8; ++i) {
      f4 kq, vq;
      kq.x = elu1(ak[i][0]); kq.y = elu1(ak[i][1]);
      kq.z = elu1(ak[i][2]); kq.w = elu1(ak[i][3]);
      vq.x = av[i][0]; vq.y = av[i][1]; vq.z = av[i][2]; vq.w = av[i][3];
      const int r = tr + 16 * i;
      *reinterpret_cast<f4*>(kl + r * 64 + (tc << 2)) = kq;
      *reinterpret_cast<f4*>(vl + r * 64 + (tc << 2)) = vq;
    }
    __syncthreads();
    // kv[4tr+i][4tc+j] += sum_r k[r][4tr+i] * v[r][4tc+j]
    for (int r = 0; r < 128; ++r) {
      const f4 kr = *reinterpret_cast<const f4*>(kl + r * 64 + (tr << 2));
      const f4 vr = *reinterpret_cast<const f4*>(vl + r * 64 + (tc << 2));
      const float ka[4] = {kr.x, kr.y, kr.z, kr.w};
      const float va[4] = {vr.x, vr.y, vr.z, vr.w};
#pragma unroll
      for (int i = 0; i < 4; ++i)
#pragma unroll
        for (int j = 0; j < 4; ++j)
          kvacc[i][j] = fmaf(ka[i], va[j], kvacc[i][j]);
    }
    if (t < 64) {
      float s = 0.f;
      for (int r = 0; r < 128; ++r) s += kl[r * 64 + t];
      ksacc += s;
    }
  }

  float* kvp = kv_part + ((size_t)bh * nsplit + split) * (DH * DH);
#pragma unroll
  for (int i = 0; i < 4; ++i) {
    f4 o;
    o.x = kvacc[i][0]; o.y = kvacc[i][1]; o.z = kvacc[i][2]; o.w = kvacc[i][3];
    *reinterpret_cast<f4*>(kvp + ((tr << 2) + i) * DH + (tc << 2)) = o;
  }
  if (t < 64) ksum_part[((size_t)bh * nsplit + split) * DH + t] = ksacc;
}

// ---------------------------------------------------------------------------
// K2: reduce partials -> kv[64][4096], ksum[64][64]
// ---------------------------------------------------------------------------
__global__ __launch_bounds__(256) void k2_reduce(
    const float* __restrict__ kv_part, const float* __restrict__ ksum_part,
    float* __restrict__ kv, float* __restrict__ ksum, int nsplit) {
  const int bh = blockIdx.x;
  const int t = (int)threadIdx.x;
  for (int i = 0; i < 16; ++i) {
    const int idx = t + (i << 8);
    float s = 0.f;
    for (int sp = 0; sp < nsplit; ++sp)
      s += kv_part[((size_t)bh * nsplit + sp) * 4096 + idx];
    kv[(size_t)bh * 4096 + idx] = s;
  }
  if (t < DH) {
    float s = 0.f;
    for (int sp = 0; sp < nsplit; ++sp)
      s += ksum_part[((size_t)bh * nsplit + sp) * DH + t];
    ksum[(size_t)bh * DH + t] = s;
  }
}

// ---------------------------------------------------------------------------
// K3: fused q,g projection + attention apply -> attn [16384][1024] (ws)
// grid(32, 64) block(256): 128 rows x one head per block
// ---------------------------------------------------------------------------
__global__ __launch_bounds__(256) void k3_attn(
    const float* __restrict__ x, const float* __restrict__ Wq,
    const float* __restrict__ Wg, const float* __restrict__ bgp,
    const float* __restrict__ kv, const float* __restrict__ ksum,
    float* __restrict__ attn) {
  const int chunk = blockIdx.x;  // 0..31
  const int bh = blockIdx.y;
  const int b = bh >> 4, h = bh & 15;
  const int t = (int)threadIdx.x;
  const int tr = t >> 4, tc = t & 15;

  __shared__ float smem[8320 + 4096 + 64 + 128];  // ~49.3 KiB
  float* xs  = smem;               // [128][33] (gemm stage)
  float* wqs = smem + 128 * 33;    // [32][64]
  float* wgs = wqs + 32 * 64;      // [32][64]
  float* ql  = smem;               // [128][65] (attn stage, aliases, =8320)
  float* kvl = smem + 8320;        // [64][64]  (persistent)
  float* ksl = kvl + 4096;         // [64]
  float* zl  = ksl + 64;           // [128]

  // stage per-head kv state once (disjoint from gemm-stage region)
  for (int i = t; i < 4096; i += 256) kvl[i] = kv[(size_t)bh * 4096 + i];
  if (t < 64) ksl[t] = ksum[(size_t)bh * DH + t];

  const int row0 = b * SEQ + chunk * 128;
  float aq[8][4] = {{0.f}}, ag[8][4] = {{0.f}};

  for (int k0 = 0; k0 < DIM; k0 += 32) {
    __syncthreads();
#pragma unroll
    for (int it = 0; it < 4; ++it) {
      const int r = (t >> 3) + 32 * it;
      const int c = (t & 7) << 2;
      const f4 xv = *reinterpret_cast<const f4*>(
          x + (size_t)(row0 + r) * DIM + k0 + c);
      float* d = xs + r * 33 + c;
      d[0] = xv.x; d[1] = xv.y; d[2] = xv.z; d[3] = xv.w;
    }
#pragma unroll
    for (int it = 0; it < 2; ++it) {
      const int r = (t >> 4) + 16 * it;
      const int c = (t & 15) << 2;
      const size_t g = (size_t)(k0 + r) * DIM + h * DH + c;
      *reinterpret_cast<f4*>(wqs + r * 64 + c) =
          *reinterpret_cast<const f4*>(Wq + g);
      *reinterpret_cast<f4*>(wgs + r * 64 + c) =
          *reinterpret_cast<const f4*>(Wg + g);
    }
    __syncthreads();
#pragma unroll
    for (int kk = 0; kk < 32; ++kk) {
      float xr[8];
#pragma unroll
      for (int i = 0; i < 8; ++i) xr[i] = xs[(tr + 16 * i) * 33 + kk];
      const f4 wq4 = *reinterpret_cast<const f4*>(&wqs[kk * 64 + (tc << 2)]);
      const f4 wg4 = *reinterpret_cast<const f4*>(&wgs[kk * 64 + (tc << 2)]);
#pragma unroll
      for (int i = 0; i < 8; ++i) {
        aq[i][0] = fmaf(xr[i], wq4.x, aq[i][0]);
        aq[i][1] = fmaf(xr[i], wq4.y, aq[i][1]);
        aq[i][2] = fmaf(xr[i], wq4.z, aq[i][2]);
        aq[i][3] = fmaf(xr[i], wq4.w, aq[i][3]);
        ag[i][0] = fmaf(xr[i], wg4.x, ag[i][0]);
        ag[i][1] = fmaf(xr[i], wg4.y, ag[i][1]);
        ag[i][2] = fmaf(xr[i], wg4.z, ag[i][2]);
        ag[i][3] = fmaf(xr[i], wg4.w, ag[i][3]);
      }
    }
  }
  // activations: q = elu+1 ; g = sigmoid(g + bg)
  float bgv[4];
#pragma unroll
  for (int j = 0; j < 4; ++j) bgv[j] = bgp[h * DH + (tc << 2) + j];
#pragma unroll
  for (int i = 0; i < 8; ++i)
#pragma unroll
    for (int j = 0; j < 4; ++j) {
      aq[i][j] = elu1(aq[i][j]);
      ag[i][j] = 1.f / (1.f + __expf(-(ag[i][j] + bgv[j])));
    }
  __syncthreads();  // done reading xs/w tiles; write q into aliased ql
#pragma unroll
  for (int i = 0; i < 8; ++i) {
    const int r = tr + 16 * i;
#pragma unroll
    for (int j = 0; j < 4; ++j) ql[r * 65 + (tc << 2) + j] = aq[i][j];
  }
  __syncthreads();
  if (t < 128) {  // z[r] = SCALE / max(q . ksum, 1e-6)
    float s = 0.f;
    for (int d = 0; d < 64; ++d) s += ql[t * 65 + d] * ksl[d];
    zl[t] = SCALE / fmaxf(s, 1e-6f);
  }
  __syncthreads();
  float acc[8][4] = {{0.f}};
  for (int d = 0; d < 64; ++d) {
    float qv[8];
#pragma unroll
    for (int i = 0; i < 8; ++i) qv[i] = ql[(tr + 16 * i) * 65 + d];
    const f4 kv4 = *reinterpret_cast<const f4*>(&kvl[d * 64 + (tc << 2)]);
#pragma unroll
    for (int i = 0; i < 8; ++i) {
      acc[i][0] = fmaf(qv[i], kv4.x, acc[i][0]);
      acc[i][1] = fmaf(qv[i], kv4.y, acc[i][1]);
      acc[i][2] = fmaf(qv[i], kv4.z, acc[i][2]);
      acc[i][3] = fmaf(qv[i], kv4.w, acc[i][3]);
    }
  }
#pragma unroll
  for (int i = 0; i < 8; ++i) {
    const int r = tr + 16 * i;
    const float z = zl[r];
    f4 o;
    o.x = acc[i][0] * z * ag[i][0];
    o.y = acc[i][1] * z * ag[i][1];
    o.z = acc[i][2] * z * ag[i][2];
    o.w = acc[i][3] * z * ag[i][3];
    *reinterpret_cast<f4*>(
        attn + (size_t)(row0 + r) * DIM + h * DH + (tc << 2)) = o;
  }
}

// ---------------------------------------------------------------------------
// K4: out = attn @ Wo   (128x128 tiles, 8x8 per thread)
// grid(8, 128) block(256)
// ---------------------------------------------------------------------------
__global__ __launch_bounds__(256) void k4_out(
    const float* __restrict__ attn, const float* __restrict__ Wo,
    float* __restrict__ out) {
  const int cb = blockIdx.x;  // 0..7
  const int rb = blockIdx.y;  // 0..127
  const int t = (int)threadIdx.x;
  const int tr = t >> 4, tc = t & 15;
  __shared__ float as[128 * 17];
  __shared__ float bs[16 * 128];
  const int row0 = rb * 128, col0 = cb * 128;
  float acc[8][8] = {{0.f}};

  for (int k0 = 0; k0 < DIM; k0 += 16) {
    __syncthreads();
#pragma unroll
    for (int it = 0; it < 2; ++it) {
      const int r = (t >> 2) + (it << 6);
      const int c = (t & 3) << 2;
      const f4 av = *reinterpret_cast<const f4*>(
          attn + (size_t)(row0 + r) * DIM + k0 + c);
      float* d = as + r * 17 + c;
      d[0] = av.x; d[1] = av.y; d[2] = av.z; d[3] = av.w;
      const int r2 = (t >> 5) + (it << 3);
      const int c2 = (t & 31) << 2;
      *reinterpret_cast<f4*>(bs + r2 * 128 + c2) =
          *reinterpret_cast<const f4*>(Wo + (size_t)(k0 + r2) * DIM + col0 + c2);
    }
    __syncthreads();
#pragma unroll
    for (int kk = 0; kk < 16; ++kk) {
      float ar[8];
#pragma unroll
      for (int i = 0; i < 8; ++i) ar[i] = as[(tr + 16 * i) * 17 + kk];
      const f4 b0 = *reinterpret_cast<const f4*>(&bs[kk * 128 + (tc << 2)]);
      const f4 b1 = *reinterpret_cast<const f4*>(&bs[kk * 128 + 64 + (tc << 2)]);
#pragma unroll
      for (int i = 0; i < 8; ++i) {
        acc[i][0] = fmaf(ar[i], b0.x, acc[i][0]);
        acc[i][1] = fmaf(ar[i], b0.y, acc[i][1]);
        acc[i][2] = fmaf(ar[i], b0.z, acc[i][2]);
        acc[i][3] = fmaf(ar[i], b0.w, acc[i][3]);
        acc[i][4] = fmaf(ar[i], b1.x, acc[i][4]);
        acc[i][5] = fmaf(ar[i], b1.y, acc[i][5]);
        acc[i][6] = fmaf(ar[i], b1.z, acc[i][6]);
        acc[i][7] = fmaf(ar[i], b1.w, acc[i][7]);
      }
    }
  }
#pragma unroll
  for (int i = 0; i < 8; ++i) {
    const size_t o = (size_t)(row0 + tr + 16 * i) * DIM + col0;
    f4 o0, o1;
    o0.x = acc[i][0]; o0.y = acc[i][1]; o0.z = acc[i][2]; o0.w = acc[i][3];
    o1.x = acc[i][4]; o1.y = acc[i][5]; o1.z = acc[i][6]; o1.w = acc[i][7];
    *reinterpret_cast<f4*>(out + o + (tc << 2)) = o0;
    *reinterpret_cast<f4*>(out + o + 64 + (tc << 2)) = o1;
  }
}

// ---------------------------------------------------------------------------
extern "C" void kernel_launch(void* const* d_in, const int* in_sizes, int n_in,
                              void* d_out, int out_size, void* d_ws,
                              size_t ws_size, hipStream_t stream) {
  const float* x  = (const float*)d_in[0];
  const float* Wq = (const float*)d_in[1];
  const float* Wk = (const float*)d_in[2];
  const float* Wv = (const float*)d_in[3];
  const float* Wg = (const float*)d_in[4];
  const float* bg = (const float*)d_in[5];
  const float* Wo = (const float*)d_in[6];
  float* out = (float*)d_out;
  float* ws = (float*)d_ws;

  const size_t attn_f = (size_t)ROWS * DIM;  // 16,777,216 floats (64 MiB)

  // pick nsplit so everything fits in ws (deterministic for fixed ws_size)
  int nsplit = 16;
  while (nsplit > 1) {
    const size_t need =
        (attn_f + 64ull * nsplit * 4096 + 64ull * nsplit * 64 +
         64ull * 4096 + 4096ull) * 4ull;
    if (need <= ws_size) break;
    nsplit >>= 1;
  }

  float* attn      = ws;
  float* kv_part   = ws + attn_f;
  float* ksum_part = kv_part + (size_t)64 * nsplit * 4096;
  float* kv        = ksum_part + (size_t)64 * nsplit * 64;
  float* ksum      = kv + 64 * 4096;

  k1_kv<<<dim3(nsplit, 64), 256, 0, stream>>>(x, Wk, Wv, kv_part, ksum_part,
                                              nsplit);
  k2_reduce<<<dim3(64), 256, 0, stream>>>(kv_part, ksum_part, kv, ksum,
                                          nsplit);
  k3_attn<<<dim3(32, 64), 256, 0, stream>>>(x, Wq, Wg, bg, kv, ksum, attn);
  k4_out<<<dim3(8, 128), 256, 0, stream>>>(attn, Wo, out);
}

// Round 2
// 436.571 us; speedup vs baseline: 5.2155x; 5.2155x over previous
//
#include <hip/hip_runtime.h>
#include <math.h>

#define DIM 1024
#define ROWS 16384
#define SCALE 0.125f

typedef __attribute__((ext_vector_type(8))) short bh8;
typedef __attribute__((ext_vector_type(4))) short bh4;
typedef __attribute__((ext_vector_type(4))) float f4v;

__device__ __forceinline__ unsigned short f2bf(float f) {
  unsigned u = __builtin_bit_cast(unsigned, f);
  return (unsigned short)((u + 0x7FFFu + ((u >> 16) & 1u)) >> 16);
}
__device__ __forceinline__ float bf2f(unsigned short u) {
  return __builtin_bit_cast(float, (unsigned)u << 16);
}
__device__ __forceinline__ float elu1(float v) {
  return v > 0.f ? v + 1.f : __expf(v);
}
__device__ __forceinline__ f4v mfma16(bh8 a, bh8 b, f4v c) {
  return __builtin_amdgcn_mfma_f32_16x16x32_bf16(a, b, c, 0, 0, 0);
}

// ---- staging helpers -------------------------------------------------------
// LDS tile = 128 rows x 64 bf16 (k-contiguous), stored as 1024 16B-chunks with
// chunk swizzle q = c ^ ((c>>3)&7)  (involution; spreads banks on frag reads)

typedef const void __attribute__((address_space(1)))* gas1_t;
typedef void __attribute__((address_space(3)))* las3_t;

// global bf16 (k-contiguous, ldg halves) -> LDS, via global_load_lds w/ source
// pre-swizzle so LDS image is the swizzled layout.
__device__ __forceinline__ void gll_tile(const unsigned short* g, int ldg,
                                         unsigned short* lds, int t) {
  const int lane = t & 63, w = t >> 6;
#pragma unroll
  for (int cc = 0; cc < 4; ++cc) {
    const int base = (w * 4 + cc) * 64;  // wave-uniform dest chunk base
    const int q = base + lane;
    const int c = q ^ ((q >> 3) & 7);
    const int row = c >> 3, k8 = c & 7;
    __builtin_amdgcn_global_load_lds(
        (gas1_t)(const void*)(g + (size_t)row * ldg + k8 * 8),
        (las3_t)(void*)(lds + (size_t)base * 8), 16, 0, 0);
  }
}

// fp32 global x -> cvt bf16 -> swizzled LDS (reg-staged)
__device__ __forceinline__ void stage_x(const float* g, unsigned short* lds,
                                        int t) {
#pragma unroll
  for (int i = 0; i < 4; ++i) {
    const int c = i * 256 + t;
    const int row = c >> 3, k8 = c & 7;
    const float4 a = *reinterpret_cast<const float4*>(g + (size_t)row * DIM + k8 * 8);
    const float4 b = *reinterpret_cast<const float4*>(g + (size_t)row * DIM + k8 * 8 + 4);
    const int q = c ^ (row & 7);
    bh8 v;
    v[0] = (short)f2bf(a.x); v[1] = (short)f2bf(a.y);
    v[2] = (short)f2bf(a.z); v[3] = (short)f2bf(a.w);
    v[4] = (short)f2bf(b.x); v[5] = (short)f2bf(b.y);
    v[6] = (short)f2bf(b.z); v[7] = (short)f2bf(b.w);
    *reinterpret_cast<bh8*>(lds + q * 8) = v;
  }
}

__device__ __forceinline__ bh8 frag(const unsigned short* lds, int row, int k8) {
  const int q = ((row << 3) | k8) ^ (row & 7);
  return *reinterpret_cast<const bh8*>(lds + q * 8);
}

// 128x128 projection tile: acc += x[128xK] @ W[Kx128], K=1024
template <bool XPRE>
__device__ __forceinline__ void proj_tile(const float* xrow,
                                          const unsigned short* xbrow,
                                          const unsigned short* wt,
                                          unsigned short* sA, unsigned short* sB,
                                          int t, int lane, int wr, int wc,
                                          f4v (&acc)[4][4]) {
  const int g = lane >> 4, c0 = lane & 15;
  for (int k0 = 0; k0 < DIM; k0 += 64) {
    __syncthreads();
    if (XPRE) gll_tile(xbrow + k0, DIM, sA, t);
    else      stage_x(xrow + k0, sA, t);
    gll_tile(wt + k0, DIM, sB, t);
    __syncthreads();
#pragma unroll
    for (int kf = 0; kf < 2; ++kf) {
      bh8 af[4], bf[4];
#pragma unroll
      for (int i = 0; i < 4; ++i) af[i] = frag(sA, wr * 64 + i * 16 + c0, kf * 4 + g);
#pragma unroll
      for (int j = 0; j < 4; ++j) bf[j] = frag(sB, wc * 64 + j * 16 + c0, kf * 4 + g);
#pragma unroll
      for (int i = 0; i < 4; ++i)
#pragma unroll
        for (int j = 0; j < 4; ++j)
          acc[i][j] = mfma16(af[i], bf[j], acc[i][j]);
    }
  }
}

// ---- P0: x fp32 -> bf16 ----------------------------------------------------
__global__ __launch_bounds__(256) void p0(const float* __restrict__ x,
                                          unsigned short* __restrict__ xb) {
  const size_t i = ((size_t)blockIdx.x * 256 + threadIdx.x) * 8;
  const float4 a = *reinterpret_cast<const float4*>(x + i);
  const float4 b = *reinterpret_cast<const float4*>(x + i + 4);
  bh8 v;
  v[0] = (short)f2bf(a.x); v[1] = (short)f2bf(a.y);
  v[2] = (short)f2bf(a.z); v[3] = (short)f2bf(a.w);
  v[4] = (short)f2bf(b.x); v[5] = (short)f2bf(b.y);
  v[6] = (short)f2bf(b.z); v[7] = (short)f2bf(b.w);
  *reinterpret_cast<bh8*>(xb + i) = v;
}

// ---- P1: transpose+cvt weights into head-interleaved [col][k] bf16 ---------
__global__ __launch_bounds__(256) void p1(
    const float* __restrict__ Wq, const float* __restrict__ Wg,
    const float* __restrict__ Wk, const float* __restrict__ Wv,
    const float* __restrict__ Wo, unsigned short* __restrict__ WqgT,
    unsigned short* __restrict__ WkvT, unsigned short* __restrict__ WoT) {
  const int m = blockIdx.z;
  const int tc = blockIdx.x, tr = blockIdx.y;
  const int t = threadIdx.x;
  const float* src = m == 0 ? Wq : m == 1 ? Wg : m == 2 ? Wk : m == 3 ? Wv : Wo;
  __shared__ float tile[64][65];
#pragma unroll
  for (int i = 0; i < 4; ++i) {
    const int idx = i * 256 + t;
    const int r = idx >> 4;
    const int c4 = (idx & 15) * 4;
    const float4 v = *reinterpret_cast<const float4*>(
        src + (size_t)(tr * 64 + r) * DIM + tc * 64 + c4);
    tile[r][c4] = v.x; tile[r][c4 + 1] = v.y;
    tile[r][c4 + 2] = v.z; tile[r][c4 + 3] = v.w;
  }
  __syncthreads();
  unsigned short* dst = (m < 2) ? WqgT : (m < 4) ? WkvT : WoT;
  const int slot = (m == 1 || m == 3) ? 1 : 0;
#pragma unroll
  for (int i = 0; i < 4; ++i) {
    const int idx = i * 256 + t;
    const int lc = idx >> 4;
    const int k4i = (idx & 15) * 4;
    const size_t drow = (m == 4) ? (size_t)(tc * 64 + lc)
                                 : (size_t)(tc * 128 + slot * 64 + lc);
    bh4 v;
#pragma unroll
    for (int jj = 0; jj < 4; ++jj) v[jj] = (short)f2bf(tile[k4i + jj][lc]);
    *reinterpret_cast<bh4*>(dst + drow * DIM + tr * 64 + k4i) = v;
  }
}

// ---- K1: k,v projection + kv/ksum partials ---------------------------------
template <bool XPRE>
__global__ __launch_bounds__(256) void k1(
    const float* __restrict__ x, const unsigned short* __restrict__ xb,
    const unsigned short* __restrict__ WkvT, float* __restrict__ kv_part,
    float* __restrict__ ksum_part) {
  const int h = blockIdx.x, rb = blockIdx.y;
  const int b = rb >> 3, split = rb & 7;
  const int bh = b * 16 + h;
  const int t = threadIdx.x, lane = t & 63, w = t >> 6, wr = w >> 1, wc = w & 1;
  const int g = lane >> 4, c0 = lane & 15;
  __shared__ unsigned short sA[8192];  // x tile / kT (64 d x 128 n swizzled)
  __shared__ unsigned short sB[8192];  // W tile / vT
  __shared__ float ksp[256];
  f4v kvacc[4];
#pragma unroll
  for (int e = 0; e < 4; ++e) kvacc[e] = (f4v){0.f, 0.f, 0.f, 0.f};
  float ksacc = 0.f;
  const unsigned short* wt = WkvT + (size_t)h * 128 * DIM;
  for (int st = 0; st < 4; ++st) {
    const int row0 = rb * 512 + st * 128;
    f4v acc[4][4];
#pragma unroll
    for (int i = 0; i < 4; ++i)
#pragma unroll
      for (int j = 0; j < 4; ++j) acc[i][j] = (f4v){0.f, 0.f, 0.f, 0.f};
    proj_tile<XPRE>(x + (size_t)row0 * DIM, xb + (size_t)row0 * DIM, wt, sA, sB,
                    t, lane, wr, wc, acc);
    __syncthreads();
    // transposed write: kT (elu) into sA, vT into sB. layout [d][n]:
    // chunk = (d<<4) | ((n>>3) ^ (d&7))
    unsigned short* dst = wc ? sB : sA;
#pragma unroll
    for (int i = 0; i < 4; ++i)
#pragma unroll
      for (int j = 0; j < 4; ++j) {
        const int d = j * 16 + c0;
        const int n = wr * 64 + i * 16 + g * 4;
        const int q = (d << 4) | (((n >> 3) ^ (d & 7)) & 15);
        bh4 v;
#pragma unroll
        for (int r = 0; r < 4; ++r) {
          float f = acc[i][j][r];
          if (!wc) f = elu1(f);
          v[r] = (short)f2bf(f);
        }
        *reinterpret_cast<bh4*>(dst + q * 8 + (n & 7)) = v;
      }
    __syncthreads();
    // ksum partial from kT
    {
      const int d = t & 63, ng = t >> 6;
      float s = 0.f;
#pragma unroll
      for (int nn = 0; nn < 32; ++nn) {
        const int n = ng * 32 + nn;
        const int q = (d << 4) | (((n >> 3) ^ (d & 7)) & 15);
        s += bf2f(sA[q * 8 + (n & 7)]);
      }
      ksacc += s;
    }
    // kv partial: kv[d][e] += sum_n kT[d][n]*vT[e][n]; wave w owns d-tile w
#pragma unroll
    for (int kf = 0; kf < 4; ++kf) {
      const int d = w * 16 + c0;
      const int n8 = kf * 4 + g;
      const int qa = (d << 4) | ((n8 ^ (d & 7)) & 15);
      const bh8 ak = *reinterpret_cast<const bh8*>(sA + qa * 8);
#pragma unroll
      for (int et = 0; et < 4; ++et) {
        const int e = et * 16 + c0;
        const int qb = (e << 4) | ((n8 ^ (e & 7)) & 15);
        const bh8 bv = *reinterpret_cast<const bh8*>(sB + qb * 8);
        kvacc[et] = mfma16(ak, bv, kvacc[et]);
      }
    }
  }
  float* kp = kv_part + ((size_t)bh * 8 + split) * 4096;
#pragma unroll
  for (int et = 0; et < 4; ++et)
#pragma unroll
    for (int r = 0; r < 4; ++r)
      kp[(w * 16 + (lane >> 4) * 4 + r) * 64 + et * 16 + (lane & 15)] =
          kvacc[et][r];
  ksp[t] = ksacc;
  __syncthreads();
  if (t < 64)
    ksum_part[((size_t)bh * 8 + split) * 64 + t] =
        ksp[t] + ksp[t + 64] + ksp[t + 128] + ksp[t + 192];
}

// ---- K2: reduce partials -> kvT bf16 [bh][e][d], ksum fp32 -----------------
__global__ __launch_bounds__(256) void k2(const float* __restrict__ kv_part,
                                          const float* __restrict__ ksum_part,
                                          unsigned short* __restrict__ kvT,
                                          float* __restrict__ ksum) {
  const int bh = blockIdx.x, t = threadIdx.x;
#pragma unroll
  for (int i = 0; i < 16; ++i) {
    const int idx = i * 256 + t;
    const int d = idx >> 6, e = idx & 63;
    float s = 0.f;
    for (int sp = 0; sp < 8; ++sp)
      s += kv_part[((size_t)bh * 8 + sp) * 4096 + idx];
    kvT[(size_t)bh * 4096 + e * 64 + d] = f2bf(s);
  }
  if (t < 64) {
    float s = 0.f;
    for (int sp = 0; sp < 8; ++sp)
      s += ksum_part[((size_t)bh * 8 + sp) * 64 + t];
    ksum[bh * 64 + t] = s;
  }
}

// ---- K3: q,g projection + q@kv + gate -> attn bf16 -------------------------
template <bool XPRE>
__global__ __launch_bounds__(256) void k3(
    const float* __restrict__ x, const unsigned short* __restrict__ xb,
    const unsigned short* __restrict__ WqgT,
    const unsigned short* __restrict__ kvT, const float* __restrict__ ksum,
    const float* __restrict__ bg, unsigned short* __restrict__ attn) {
  const int h = blockIdx.x, rb = blockIdx.y;
  const int b = rb >> 3;
  const int bh = b * 16 + h;
  const int t = threadIdx.x, lane = t & 63, w = t >> 6, wr = w >> 1, wc = w & 1;
  const int g = lane >> 4, c0 = lane & 15;
  __shared__ unsigned short sA[8192];   // x tile / q_lds (swizzled [n][d])
  __shared__ unsigned short sB[8192];   // W tile / g_lds
  __shared__ unsigned short skv[64 * 72];  // kvT [e][d] padded
  __shared__ float sden[128];
  __shared__ float sks[64];
  for (int i = t; i < 4096; i += 256)
    skv[(i >> 6) * 72 + (i & 63)] = kvT[(size_t)bh * 4096 + i];
  if (t < 64) sks[t] = ksum[bh * 64 + t];
  float bgv[4];
#pragma unroll
  for (int j = 0; j < 4; ++j) bgv[j] = bg[h * 64 + j * 16 + c0];
  const unsigned short* wt = WqgT + (size_t)h * 128 * DIM;
  for (int st = 0; st < 4; ++st) {
    const int row0 = rb * 512 + st * 128;
    f4v acc[4][4];
#pragma unroll
    for (int i = 0; i < 4; ++i)
#pragma unroll
      for (int j = 0; j < 4; ++j) acc[i][j] = (f4v){0.f, 0.f, 0.f, 0.f};
    proj_tile<XPRE>(x + (size_t)row0 * DIM, xb + (size_t)row0 * DIM, wt, sA, sB,
                    t, lane, wr, wc, acc);
    __syncthreads();
    if (wc == 0) {  // q: elu, den (q.ksum), write bf16 q into sA
#pragma unroll
      for (int i = 0; i < 4; ++i) {
        float qa[4][4];
        float dp[4] = {0.f, 0.f, 0.f, 0.f};
#pragma unroll
        for (int j = 0; j < 4; ++j)
#pragma unroll
          for (int r = 0; r < 4; ++r) {
            const float f = elu1(acc[i][j][r]);
            qa[j][r] = f;
            dp[r] += f * sks[j * 16 + c0];
          }
#pragma unroll
        for (int r = 0; r < 4; ++r) {
#pragma unroll
          for (int m = 1; m < 16; m <<= 1) dp[r] += __shfl_xor(dp[r], m, 64);
        }
        const int rowb = wr * 64 + i * 16 + g * 4;
        if (c0 == 0) {
#pragma unroll
          for (int r = 0; r < 4; ++r) sden[rowb + r] = dp[r];
        }
#pragma unroll
        for (int j = 0; j < 4; ++j) {
          const int d = j * 16 + c0;
#pragma unroll
          for (int r = 0; r < 4; ++r) {
            const int row = rowb + r;
            const int q = ((row << 3) | (d >> 3)) ^ (row & 7);
            sA[q * 8 + (d & 7)] = f2bf(qa[j][r]);
          }
        }
      }
    } else {  // g: sigmoid(acc+bg) -> sB
#pragma unroll
      for (int i = 0; i < 4; ++i)
#pragma unroll
        for (int j = 0; j < 4; ++j) {
          const int d = j * 16 + c0;
#pragma unroll
          for (int r = 0; r < 4; ++r) {
            const int row = wr * 64 + i * 16 + g * 4 + r;
            const float f = 1.f / (1.f + __expf(-(acc[i][j][r] + bgv[j])));
            const int q = ((row << 3) | (d >> 3)) ^ (row & 7);
            sB[q * 8 + (d & 7)] = f2bf(f);
          }
        }
    }
    __syncthreads();
    // q@kv: wave w -> rows [w*32, w*32+32)
    f4v oacc[2][4];
#pragma unroll
    for (int ii = 0; ii < 2; ++ii)
#pragma unroll
      for (int et = 0; et < 4; ++et) oacc[ii][et] = (f4v){0.f, 0.f, 0.f, 0.f};
#pragma unroll
    for (int kf = 0; kf < 2; ++kf) {
      bh8 aq[2];
#pragma unroll
      for (int ii = 0; ii < 2; ++ii)
        aq[ii] = frag(sA, w * 32 + ii * 16 + c0, kf * 4 + g);
#pragma unroll
      for (int et = 0; et < 4; ++et) {
        const bh8 bkv = *reinterpret_cast<const bh8*>(
            skv + (et * 16 + c0) * 72 + kf * 32 + g * 8);
#pragma unroll
        for (int ii = 0; ii < 2; ++ii)
          oacc[ii][et] = mfma16(aq[ii], bkv, oacc[ii][et]);
      }
    }
#pragma unroll
    for (int ii = 0; ii < 2; ++ii)
#pragma unroll
      for (int et = 0; et < 4; ++et)
#pragma unroll
        for (int r = 0; r < 4; ++r) {
          const int row = w * 32 + ii * 16 + g * 4 + r;
          const int e = et * 16 + c0;
          const int qg = ((row << 3) | (e >> 3)) ^ (row & 7);
          const float gv = bf2f(sB[qg * 8 + (e & 7)]);
          const float z = SCALE / fmaxf(sden[row], 1e-6f);
          attn[(size_t)(row0 + row) * DIM + h * 64 + e] =
              f2bf(oacc[ii][et][r] * z * gv);
        }
  }
}

// ---- K4: out = attn @ Wo ----------------------------------------------------
__global__ __launch_bounds__(256) void k4(const unsigned short* __restrict__ attn,
                                          const unsigned short* __restrict__ WoT,
                                          float* __restrict__ out) {
  const int cb = blockIdx.x, rbk = blockIdx.y;
  const int t = threadIdx.x, lane = t & 63, w = t >> 6, wr = w >> 1, wc = w & 1;
  const int g = lane >> 4, c0 = lane & 15;
  __shared__ unsigned short sA[8192], sB[8192];
  f4v acc[4][4];
#pragma unroll
  for (int i = 0; i < 4; ++i)
#pragma unroll
    for (int j = 0; j < 4; ++j) acc[i][j] = (f4v){0.f, 0.f, 0.f, 0.f};
  const unsigned short* arow = attn + (size_t)rbk * 128 * DIM;
  const unsigned short* wt = WoT + (size_t)cb * 128 * DIM;
  for (int k0 = 0; k0 < DIM; k0 += 64) {
    __syncthreads();
    gll_tile(arow + k0, DIM, sA, t);
    gll_tile(wt + k0, DIM, sB, t);
    __syncthreads();
#pragma unroll
    for (int kf = 0; kf < 2; ++kf) {
      bh8 af[4], bf[4];
#pragma unroll
      for (int i = 0; i < 4; ++i) af[i] = frag(sA, wr * 64 + i * 16 + c0, kf * 4 + g);
#pragma unroll
      for (int j = 0; j < 4; ++j) bf[j] = frag(sB, wc * 64 + j * 16 + c0, kf * 4 + g);
#pragma unroll
      for (int i = 0; i < 4; ++i)
#pragma unroll
        for (int j = 0; j < 4; ++j)
          acc[i][j] = mfma16(af[i], bf[j], acc[i][j]);
    }
  }
#pragma unroll
  for (int i = 0; i < 4; ++i)
#pragma unroll
    for (int j = 0; j < 4; ++j)
#pragma unroll
      for (int r = 0; r < 4; ++r)
        out[(size_t)(rbk * 128 + wr * 64 + i * 16 + g * 4 + r) * DIM +
            cb * 128 + wc * 64 + j * 16 + c0] = acc[i][j][r];
}

// ---------------------------------------------------------------------------
extern "C" void kernel_launch(void* const* d_in, const int* in_sizes, int n_in,
                              void* d_out, int out_size, void* d_ws,
                              size_t ws_size, hipStream_t stream) {
  const float* x  = (const float*)d_in[0];
  const float* Wq = (const float*)d_in[1];
  const float* Wk = (const float*)d_in[2];
  const float* Wv = (const float*)d_in[3];
  const float* Wg = (const float*)d_in[4];
  const float* bg = (const float*)d_in[5];
  const float* Wo = (const float*)d_in[6];
  float* out = (float*)d_out;
  char* w = (char*)d_ws;

  unsigned short* attn      = (unsigned short*)(w + 0);          // 32 MiB
  unsigned short* WqgT      = (unsigned short*)(w + 33554432);   // 4 MiB
  unsigned short* WkvT      = (unsigned short*)(w + 37748736);   // 4 MiB
  unsigned short* WoT       = (unsigned short*)(w + 41943040);   // 2 MiB
  unsigned short* kvT       = (unsigned short*)(w + 44040192);   // 512 KiB
  float*          ksum      = (float*)(w + 44564480);            // 16 KiB
  float*          kv_part   = (float*)(w + 44580864);            // 8 MiB
  float*          ksum_part = (float*)(w + 52969472);            // 128 KiB
  unsigned short* xb        = (unsigned short*)(w + 53100544);   // 32 MiB (opt)
  const bool xpre = ws_size >= (size_t)86654976;

  p1<<<dim3(16, 16, 5), 256, 0, stream>>>(Wq, Wg, Wk, Wv, Wo, WqgT, WkvT, WoT);
  if (xpre) {
    p0<<<8192, 256, 0, stream>>>(x, xb);
    k1<true><<<dim3(16, 32), 256, 0, stream>>>(x, xb, WkvT, kv_part, ksum_part);
    k2<<<64, 256, 0, stream>>>(kv_part, ksum_part, kvT, ksum);
    k3<true><<<dim3(16, 32), 256, 0, stream>>>(x, xb, WqgT, kvT, ksum, bg, attn);
  } else {
    k1<false><<<dim3(16, 32), 256, 0, stream>>>(x, xb, WkvT, kv_part, ksum_part);
    k2<<<64, 256, 0, stream>>>(kv_part, ksum_part, kvT, ksum);
    k3<false><<<dim3(16, 32), 256, 0, stream>>>(x, xb, WqgT, kvT, ksum, bg, attn);
  }
  k4<<<dim3(8, 128), 256, 0, stream>>>(attn, WoT, out);
}

// Round 3
// 361.514 us; speedup vs baseline: 6.2983x; 1.2076x over previous
//
#include <hip/hip_runtime.h>
#include <math.h>

#define DIM 1024
#define SCALE 0.125f

typedef __attribute__((ext_vector_type(8))) short bh8;
typedef __attribute__((ext_vector_type(4))) short bh4;
typedef __attribute__((ext_vector_type(4))) float f4v;

__device__ __forceinline__ unsigned short f2bf(float f) {
  unsigned u = __builtin_bit_cast(unsigned, f);
  return (unsigned short)((u + 0x7FFFu + ((u >> 16) & 1u)) >> 16);
}
__device__ __forceinline__ float bf2f(unsigned short u) {
  return __builtin_bit_cast(float, (unsigned)u << 16);
}
__device__ __forceinline__ float elu1(float v) {
  return v > 0.f ? v + 1.f : __expf(v);
}
__device__ __forceinline__ f4v mfma16(bh8 a, bh8 b, f4v c) {
  return __builtin_amdgcn_mfma_f32_16x16x32_bf16(a, b, c, 0, 0, 0);
}

typedef const void __attribute__((address_space(1)))* gas1_t;
typedef void __attribute__((address_space(3)))* las3_t;

// LDS tile = 128 rows x 64 bf16, stored as 1024 16B-chunks, chunk swizzle
// q = c ^ ((c>>3)&7). Source pre-swizzled so LDS image is swizzled layout.
__device__ __forceinline__ void gll_tile(const unsigned short* g, int ldg,
                                         unsigned short* lds, int t) {
  const int lane = t & 63, w = t >> 6;
#pragma unroll
  for (int cc = 0; cc < 4; ++cc) {
    const int base = (w * 4 + cc) * 64;  // wave-uniform dest chunk base
    const int q = base + lane;
    const int c = q ^ ((q >> 3) & 7);
    const int row = c >> 3, k8 = c & 7;
    __builtin_amdgcn_global_load_lds(
        (gas1_t)(const void*)(g + (size_t)row * ldg + k8 * 8),
        (las3_t)(void*)(lds + (size_t)base * 8), 16, 0, 0);
  }
}

__device__ __forceinline__ bh8 frag(const unsigned short* lds, int row, int k8) {
  const int q = ((row << 3) | k8) ^ (row & 7);
  return *reinterpret_cast<const bh8*>(lds + q * 8);
}

// ---- P0: x fp32 -> bf16 (per pass) -----------------------------------------
__global__ __launch_bounds__(256) void p0(const float* __restrict__ x,
                                          unsigned short* __restrict__ xb) {
  const size_t i = ((size_t)blockIdx.x * 256 + threadIdx.x) * 8;
  const float4 a = *reinterpret_cast<const float4*>(x + i);
  const float4 b = *reinterpret_cast<const float4*>(x + i + 4);
  bh8 v;
  v[0] = (short)f2bf(a.x); v[1] = (short)f2bf(a.y);
  v[2] = (short)f2bf(a.z); v[3] = (short)f2bf(a.w);
  v[4] = (short)f2bf(b.x); v[5] = (short)f2bf(b.y);
  v[6] = (short)f2bf(b.z); v[7] = (short)f2bf(b.w);
  *reinterpret_cast<bh8*>(xb + i) = v;
}

// ---- P1: weights fp32 -> bf16 transposed -----------------------------------
// WallT[(h*4+m)*64+e][k] = Wm[k][h*64+e], m: 0=q,1=k,2=v,3=g.  WoT[c][k]=Wo[k][c]
__global__ __launch_bounds__(256) void p1(
    const float* __restrict__ Wq, const float* __restrict__ Wk,
    const float* __restrict__ Wv, const float* __restrict__ Wg,
    const float* __restrict__ Wo, unsigned short* __restrict__ WallT,
    unsigned short* __restrict__ WoT) {
  const int m = blockIdx.z;
  const int tc = blockIdx.x, tr = blockIdx.y;
  const int t = threadIdx.x;
  const float* src = m == 0 ? Wq : m == 1 ? Wk : m == 2 ? Wv : m == 3 ? Wg : Wo;
  __shared__ float tile[64][65];
#pragma unroll
  for (int i = 0; i < 4; ++i) {
    const int idx = i * 256 + t;
    const int r = idx >> 4;
    const int c4 = (idx & 15) * 4;
    const float4 v = *reinterpret_cast<const float4*>(
        src + (size_t)(tr * 64 + r) * DIM + tc * 64 + c4);
    tile[r][c4] = v.x; tile[r][c4 + 1] = v.y;
    tile[r][c4 + 2] = v.z; tile[r][c4 + 3] = v.w;
  }
  __syncthreads();
  unsigned short* dst = (m < 4) ? WallT : WoT;
#pragma unroll
  for (int i = 0; i < 4; ++i) {
    const int idx = i * 256 + t;
    const int lc = idx >> 4;       // local col
    const int k4i = (idx & 15) * 4;
    const size_t drow = (m < 4) ? (size_t)(tc * 256 + m * 64 + lc)
                                : (size_t)(tc * 64 + lc);
    bh4 v;
#pragma unroll
    for (int jj = 0; jj < 4; ++jj) v[jj] = (short)f2bf(tile[k4i + jj][lc]);
    *reinterpret_cast<bh4*>(dst + drow * DIM + tr * 64 + k4i) = v;
  }
}

// ---- G1: qkvg = xb @ WallT, fused activations (128x128 tile, m97-style) ----
__global__ __launch_bounds__(256) void g1(
    const unsigned short* __restrict__ xb,
    const unsigned short* __restrict__ WallT, const float* __restrict__ bg,
    unsigned short* __restrict__ qkvg) {
  const int cb = blockIdx.x, rb = blockIdx.y;
  const int t = threadIdx.x, lane = t & 63, w = t >> 6, wr = w >> 1, wc = w & 1;
  const int g4 = lane >> 4, c0 = lane & 15;
  __shared__ unsigned short sA[8192], sB[8192];
  f4v acc[4][4];
#pragma unroll
  for (int i = 0; i < 4; ++i)
#pragma unroll
    for (int j = 0; j < 4; ++j) acc[i][j] = (f4v){0.f, 0.f, 0.f, 0.f};
  const unsigned short* arow = xb + (size_t)rb * 128 * DIM;
  const unsigned short* brow = WallT + (size_t)cb * 128 * DIM;
  for (int k0 = 0; k0 < DIM; k0 += 64) {
    __syncthreads();
    gll_tile(arow + k0, DIM, sA, t);
    gll_tile(brow + k0, DIM, sB, t);
    __syncthreads();
#pragma unroll
    for (int kf = 0; kf < 2; ++kf) {
      bh8 af[4], bf[4];
#pragma unroll
      for (int i = 0; i < 4; ++i) af[i] = frag(sA, wr * 64 + i * 16 + c0, kf * 4 + g4);
#pragma unroll
      for (int j = 0; j < 4; ++j) bf[j] = frag(sB, wc * 64 + j * 16 + c0, kf * 4 + g4);
#pragma unroll
      for (int i = 0; i < 4; ++i)
#pragma unroll
        for (int j = 0; j < 4; ++j)
          acc[i][j] = mfma16(af[i], bf[j], acc[i][j]);
    }
  }
  // epilogue: col type m (wave-uniform), activation, bf16 store
  const int colbase = cb * 128 + wc * 64;
  const int m = (colbase >> 6) & 3, h = colbase >> 8;
  float bgv[4];
#pragma unroll
  for (int j = 0; j < 4; ++j)
    bgv[j] = (m == 3) ? bg[h * 64 + j * 16 + c0] : 0.f;
#pragma unroll
  for (int i = 0; i < 4; ++i)
#pragma unroll
    for (int j = 0; j < 4; ++j)
#pragma unroll
      for (int r = 0; r < 4; ++r) {
        float v = acc[i][j][r];
        if (m <= 1) v = elu1(v);                       // q, k
        else if (m == 3) v = 1.f / (1.f + __expf(-(v + bgv[j])));  // g
        const int row = rb * 128 + wr * 64 + i * 16 + g4 * 4 + r;
        qkvg[(size_t)row * 4096 + colbase + j * 16 + c0] = f2bf(v);
      }
}

// ---- G2: kv-state partials (fp32 outer product), 128 rows per block --------
__global__ __launch_bounds__(256) void g2(const unsigned short* __restrict__ qkvg,
                                          float* __restrict__ kv_part,
                                          float* __restrict__ ksum_part) {
  const int h = blockIdx.x, z = blockIdx.y;
  const int bb = z >> 5, sp = z & 31;
  const int t = threadIdx.x, ti = t >> 4, tj = t & 15;
  __shared__ unsigned short s[128 * 128];
  float kvacc[4][4] = {{0.f}};
  float ksacc[4] = {0.f, 0.f, 0.f, 0.f};
  const unsigned short* src =
      qkvg + ((size_t)bb * 4096 + sp * 128) * 4096 + h * 256 + 64;  // k|v slots
#pragma unroll
  for (int it = 0; it < 8; ++it) {
    const int idx = it * 256 + t;
    const int r = idx >> 4, c8 = idx & 15;
    *reinterpret_cast<bh8*>(&s[r * 128 + c8 * 8]) =
        *reinterpret_cast<const bh8*>(src + (size_t)r * 4096 + c8 * 8);
  }
  __syncthreads();
  for (int r = 0; r < 128; ++r) {
    const bh4 k4 = *reinterpret_cast<const bh4*>(&s[r * 128 + 4 * ti]);
    const bh4 v4 = *reinterpret_cast<const bh4*>(&s[r * 128 + 64 + 4 * tj]);
    float kf[4], vf[4];
#pragma unroll
    for (int i = 0; i < 4; ++i) {
      kf[i] = bf2f((unsigned short)k4[i]);
      vf[i] = bf2f((unsigned short)v4[i]);
      ksacc[i] += kf[i];
    }
#pragma unroll
    for (int i = 0; i < 4; ++i)
#pragma unroll
      for (int j = 0; j < 4; ++j) kvacc[i][j] = fmaf(kf[i], vf[j], kvacc[i][j]);
  }
  float* kp = kv_part + (((size_t)(bb * 16 + h)) * 32 + sp) * 4096;
#pragma unroll
  for (int i = 0; i < 4; ++i)
#pragma unroll
    for (int j = 0; j < 4; ++j) kp[(4 * ti + i) * 64 + 4 * tj + j] = kvacc[i][j];
  if (tj == 0) {
#pragma unroll
    for (int i = 0; i < 4; ++i)
      ksum_part[(((size_t)(bb * 16 + h)) * 32 + sp) * 64 + 4 * ti + i] = ksacc[i];
  }
}

// ---- G2r: reduce partials -> kvT bf16 [bh][e][d], ksum fp32 ----------------
__global__ __launch_bounds__(256) void g2r(const float* __restrict__ kv_part,
                                           const float* __restrict__ ksum_part,
                                           unsigned short* __restrict__ kvT,
                                           float* __restrict__ ksum, int b0) {
  const int bhl = blockIdx.x, t = threadIdx.x;
  const size_t bh = (size_t)b0 * 16 + bhl;
#pragma unroll
  for (int i = 0; i < 16; ++i) {
    const int idx = i * 256 + t;
    const int d = idx >> 6, e = idx & 63;
    float s = 0.f;
    for (int sp = 0; sp < 32; ++sp)
      s += kv_part[((size_t)bhl * 32 + sp) * 4096 + idx];
    kvT[bh * 4096 + e * 64 + d] = f2bf(s);
  }
  if (t < 64) {
    float s = 0.f;
    for (int sp = 0; sp < 32; ++sp)
      s += ksum_part[((size_t)bhl * 32 + sp) * 64 + t];
    ksum[bh * 64 + t] = s;
  }
}

// ---- G3: attn apply: o = q@kv * z * g -> bf16 into k-slot of qkvg ----------
__global__ __launch_bounds__(256) void g3(unsigned short* __restrict__ qkvg,
                                          const unsigned short* __restrict__ kvT,
                                          const float* __restrict__ ksum,
                                          int b0) {
  const int h = blockIdx.x, z = blockIdx.y;
  const int t = threadIdx.x, lane = t & 63, w = t >> 6;
  const int g4 = lane >> 4, c0 = lane & 15;
  __shared__ unsigned short sQ[8192];
  __shared__ unsigned short skv[64 * 72];
  __shared__ float sks[64], sden[128];
  const int bb = z >> 5;
  const size_t bh = (size_t)(b0 + bb) * 16 + h;
  for (int i = t; i < 4096; i += 256)
    skv[(i >> 6) * 72 + (i & 63)] = kvT[bh * 4096 + i];
  if (t < 64) sks[t] = ksum[bh * 64 + t];
  const size_t row0 = (size_t)z * 128;
  gll_tile(qkvg + row0 * 4096 + h * 256, 4096, sQ, t);
  __syncthreads();
  if (t < 128) {
    float s = 0.f;
    for (int d = 0; d < 64; ++d)
      s += bf2f(sQ[((((t) << 3) | (d >> 3)) ^ (t & 7)) * 8 + (d & 7)]) * sks[d];
    sden[t] = SCALE / fmaxf(s, 1e-6f);
  }
  __syncthreads();
  f4v oacc[2][4];
#pragma unroll
  for (int ii = 0; ii < 2; ++ii)
#pragma unroll
    for (int et = 0; et < 4; ++et) oacc[ii][et] = (f4v){0.f, 0.f, 0.f, 0.f};
#pragma unroll
  for (int kf = 0; kf < 2; ++kf) {
    bh8 aq[2];
#pragma unroll
    for (int ii = 0; ii < 2; ++ii)
      aq[ii] = frag(sQ, w * 32 + ii * 16 + c0, kf * 4 + g4);
#pragma unroll
    for (int et = 0; et < 4; ++et) {
      const bh8 bkv = *reinterpret_cast<const bh8*>(
          skv + (et * 16 + c0) * 72 + kf * 32 + g4 * 8);
#pragma unroll
      for (int ii = 0; ii < 2; ++ii)
        oacc[ii][et] = mfma16(aq[ii], bkv, oacc[ii][et]);
    }
  }
#pragma unroll
  for (int ii = 0; ii < 2; ++ii)
#pragma unroll
    for (int et = 0; et < 4; ++et)
#pragma unroll
      for (int r = 0; r < 4; ++r) {
        const int row = w * 32 + ii * 16 + g4 * 4 + r;
        const int e = et * 16 + c0;
        const float gv = bf2f(qkvg[(row0 + row) * 4096 + h * 256 + 192 + e]);
        qkvg[(row0 + row) * 4096 + h * 256 + 64 + e] =
            f2bf(oacc[ii][et][r] * sden[row] * gv);
      }
}

// ---- G4: out = attn @ WoT (attn lives in k-slots of qkvg) ------------------
__global__ __launch_bounds__(256) void g4(const unsigned short* __restrict__ qkvg,
                                          const unsigned short* __restrict__ WoT,
                                          float* __restrict__ out, int b0) {
  const int cb = blockIdx.x, rb = blockIdx.y;
  const int t = threadIdx.x, lane = t & 63, w = t >> 6, wr = w >> 1, wc = w & 1;
  const int g4 = lane >> 4, c0 = lane & 15;
  __shared__ unsigned short sA[8192], sB[8192];
  f4v acc[4][4];
#pragma unroll
  for (int i = 0; i < 4; ++i)
#pragma unroll
    for (int j = 0; j < 4; ++j) acc[i][j] = (f4v){0.f, 0.f, 0.f, 0.f};
  const unsigned short* arow = qkvg + (size_t)rb * 128 * 4096;
  const unsigned short* brow = WoT + (size_t)cb * 128 * DIM;
  for (int k0 = 0; k0 < DIM; k0 += 64) {
    __syncthreads();
    // attn col c -> qkvg col (c>>6)*256 + 64 + (c&63); k0 is 64-aligned
    gll_tile(arow + (k0 >> 6) * 256 + 64, 4096, sA, t);
    gll_tile(brow + k0, DIM, sB, t);
    __syncthreads();
#pragma unroll
    for (int kf = 0; kf < 2; ++kf) {
      bh8 af[4], bf[4];
#pragma unroll
      for (int i = 0; i < 4; ++i) af[i] = frag(sA, wr * 64 + i * 16 + c0, kf * 4 + g4);
#pragma unroll
      for (int j = 0; j < 4; ++j) bf[j] = frag(sB, wc * 64 + j * 16 + c0, kf * 4 + g4);
#pragma unroll
      for (int i = 0; i < 4; ++i)
#pragma unroll
        for (int j = 0; j < 4; ++j)
          acc[i][j] = mfma16(af[i], bf[j], acc[i][j]);
    }
  }
#pragma unroll
  for (int i = 0; i < 4; ++i)
#pragma unroll
    for (int j = 0; j < 4; ++j)
#pragma unroll
      for (int r = 0; r < 4; ++r)
        out[((size_t)b0 * 4096 + rb * 128 + wr * 64 + i * 16 + g4 * 4 + r) * DIM +
            cb * 128 + wc * 64 + j * 16 + c0] = acc[i][j][r];
}

// ---------------------------------------------------------------------------
extern "C" void kernel_launch(void* const* d_in, const int* in_sizes, int n_in,
                              void* d_out, int out_size, void* d_ws,
                              size_t ws_size, hipStream_t stream) {
  const float* x  = (const float*)d_in[0];
  const float* Wq = (const float*)d_in[1];
  const float* Wk = (const float*)d_in[2];
  const float* Wv = (const float*)d_in[3];
  const float* Wg = (const float*)d_in[4];
  const float* bg = (const float*)d_in[5];
  const float* Wo = (const float*)d_in[6];
  float* out = (float*)d_out;
  char* w = (char*)d_ws;

  // adaptive batches-per-pass by ws_size (bytes):
  // base 11,026,432 + nbat * 50,462,720
  int nbat = 1;
  if (ws_size >= 11026432ull + 4ull * 50462720ull) nbat = 4;
  else if (ws_size >= 11026432ull + 2ull * 50462720ull) nbat = 2;

  unsigned short* WallT = (unsigned short*)(w);                  // 8 MiB
  unsigned short* WoT   = (unsigned short*)(w + 8388608);        // 2 MiB
  unsigned short* kvT   = (unsigned short*)(w + 10485760);       // 512 KiB
  float*          ksum  = (float*)(w + 11010048);                // 16 KiB
  char* dyn = w + 11026432;
  float* kv_part        = (float*)dyn;                           // nbat*8 MiB
  float* ksum_part      = (float*)(dyn + (size_t)nbat * 8388608);
  unsigned short* xb    = (unsigned short*)(dyn + (size_t)nbat * (8388608 + 131072));
  unsigned short* qkvg  = (unsigned short*)(dyn + (size_t)nbat * (8388608 + 131072 + 8388608));

  p1<<<dim3(16, 16, 5), 256, 0, stream>>>(Wq, Wk, Wv, Wg, Wo, WallT, WoT);

  for (int b0 = 0; b0 < 4; b0 += nbat) {
    const int rows_p = nbat * 4096;
    p0<<<rows_p / 2, 256, 0, stream>>>(x + (size_t)b0 * 4096 * DIM, xb);
    g1<<<dim3(32, rows_p / 128), 256, 0, stream>>>(xb, WallT, bg, qkvg);
    g2<<<dim3(16, nbat * 32), 256, 0, stream>>>(qkvg, kv_part, ksum_part);
    g2r<<<nbat * 16, 256, 0, stream>>>(kv_part, ksum_part, kvT, ksum, b0);
    g3<<<dim3(16, rows_p / 128), 256, 0, stream>>>(qkvg, kvT, ksum, b0);
    g4<<<dim3(8, rows_p / 128), 256, 0, stream>>>(qkvg, WoT, out, b0);
  }
}

// Round 4
// 332.703 us; speedup vs baseline: 6.8438x; 1.0866x over previous
//
#include <hip/hip_runtime.h>
#include <math.h>

#define DIM 1024
#define SCALE 0.125f
#define NT 16  // K-tiles of 64

typedef __attribute__((ext_vector_type(8))) short bh8;
typedef __attribute__((ext_vector_type(4))) short bh4;
typedef __attribute__((ext_vector_type(4))) float f4v;

__device__ __forceinline__ unsigned short f2bf(float f) {
  unsigned u = __builtin_bit_cast(unsigned, f);
  return (unsigned short)((u + 0x7FFFu + ((u >> 16) & 1u)) >> 16);
}
__device__ __forceinline__ float bf2f(unsigned short u) {
  return __builtin_bit_cast(float, (unsigned)u << 16);
}
__device__ __forceinline__ float elu1(float v) {
  return v > 0.f ? v + 1.f : __expf(v);
}
__device__ __forceinline__ f4v mfma16(bh8 a, bh8 b, f4v c) {
  return __builtin_amdgcn_mfma_f32_16x16x32_bf16(a, b, c, 0, 0, 0);
}

typedef const void __attribute__((address_space(1)))* gas1_t;
typedef void __attribute__((address_space(3)))* las3_t;

// 128x64 bf16 half-tile in LDS as 1024 16B chunks, swizzle q = c ^ ((c>>3)&7)
__device__ __forceinline__ bh8 frag(const unsigned short* lds, int row, int k8) {
  const int q = ((row << 3) | k8) ^ (row & 7);
  return *reinterpret_cast<const bh8*>(lds + q * 8);
}

// 256-thread staging helper (used by g3): 128x64 tile, 4 chunks/thread
__device__ __forceinline__ void gll_tile(const unsigned short* g, int ldg,
                                         unsigned short* lds, int t) {
  const int lane = t & 63, w = t >> 6;
#pragma unroll
  for (int cc = 0; cc < 4; ++cc) {
    const int base = (w * 4 + cc) * 64;
    const int q = base + lane;
    const int c = q ^ ((q >> 3) & 7);
    __builtin_amdgcn_global_load_lds(
        (gas1_t)(const void*)(g + (size_t)(c >> 3) * ldg + (c & 7) * 8),
        (las3_t)(void*)(lds + (size_t)base * 8), 16, 0, 0);
  }
}

// ---- P0: x fp32 -> bf16 ----------------------------------------------------
__global__ __launch_bounds__(256) void p0(const float* __restrict__ x,
                                          unsigned short* __restrict__ xb) {
  const size_t i = ((size_t)blockIdx.x * 256 + threadIdx.x) * 8;
  const float4 a = *reinterpret_cast<const float4*>(x + i);
  const float4 b = *reinterpret_cast<const float4*>(x + i + 4);
  bh8 v;
  v[0] = (short)f2bf(a.x); v[1] = (short)f2bf(a.y);
  v[2] = (short)f2bf(a.z); v[3] = (short)f2bf(a.w);
  v[4] = (short)f2bf(b.x); v[5] = (short)f2bf(b.y);
  v[6] = (short)f2bf(b.z); v[7] = (short)f2bf(b.w);
  *reinterpret_cast<bh8*>(xb + i) = v;
}

// ---- P1: weights fp32 -> bf16 transposed -----------------------------------
__global__ __launch_bounds__(256) void p1(
    const float* __restrict__ Wq, const float* __restrict__ Wk,
    const float* __restrict__ Wv, const float* __restrict__ Wg,
    const float* __restrict__ Wo, unsigned short* __restrict__ WallT,
    unsigned short* __restrict__ WoT) {
  const int m = blockIdx.z;
  const int tc = blockIdx.x, tr = blockIdx.y;
  const int t = threadIdx.x;
  const float* src = m == 0 ? Wq : m == 1 ? Wk : m == 2 ? Wv : m == 3 ? Wg : Wo;
  __shared__ float tile[64][65];
#pragma unroll
  for (int i = 0; i < 4; ++i) {
    const int idx = i * 256 + t;
    const int r = idx >> 4;
    const int c4 = (idx & 15) * 4;
    const float4 v = *reinterpret_cast<const float4*>(
        src + (size_t)(tr * 64 + r) * DIM + tc * 64 + c4);
    tile[r][c4] = v.x; tile[r][c4 + 1] = v.y;
    tile[r][c4 + 2] = v.z; tile[r][c4 + 3] = v.w;
  }
  __syncthreads();
  unsigned short* dst = (m < 4) ? WallT : WoT;
#pragma unroll
  for (int i = 0; i < 4; ++i) {
    const int idx = i * 256 + t;
    const int lc = idx >> 4;
    const int k4i = (idx & 15) * 4;
    const size_t drow = (m < 4) ? (size_t)(tc * 256 + m * 64 + lc)
                                : (size_t)(tc * 64 + lc);
    bh4 v;
#pragma unroll
    for (int jj = 0; jj < 4; ++jj) v[jj] = (short)f2bf(tile[k4i + jj][lc]);
    *reinterpret_cast<bh4*>(dst + drow * DIM + tr * 64 + k4i) = v;
  }
}

// ---- gemm8: 256x256 tile, 8-phase counted-vmcnt pipeline --------------------
// MODE 0: qkvg = xb @ WallT^T, fused activations, bf16 out (4096 cols)
// MODE 1: out = attn(k-slot of qkvg) @ WoT^T, f32 out (1024 cols)
template <int MODE>
__global__ __launch_bounds__(512, 2) void gemm8(
    const unsigned short* __restrict__ gA,
    const unsigned short* __restrict__ gB, const float* __restrict__ bg,
    unsigned short* __restrict__ ob, float* __restrict__ of) {
  const int t = threadIdx.x, lane = t & 63, w = t >> 6;
  const int wr = w >> 2, wc = w & 3, g4 = lane >> 4, c0 = lane & 15;
  const int nwg = gridDim.x;
  int bid = (int)blockIdx.x;
  bid = (bid & 7) * (nwg >> 3) + (bid >> 3);  // bijective: nwg % 8 == 0
  const int NBC = (MODE == 0) ? 16 : 4;
  const int rbn = nwg / NBC;
  const int cb = bid / rbn, rb = bid - cb * rbn;

  constexpr int LDGA = (MODE == 0) ? 1024 : 4096;
  constexpr int ASTR = (MODE == 0) ? 64 : 256;
  constexpr int AOFF = (MODE == 0) ? 0 : 64;

  __shared__ __align__(16) unsigned short lds[65536];  // 128 KiB

  // per-thread chunk offsets (2 chunks per half-tile stage)
  int offA[2], offB[2], dstc[2];
#pragma unroll
  for (int cc = 0; cc < 2; ++cc) {
    const int base = (w * 2 + cc) * 64;
    const int q = base + lane;
    const int c = q ^ ((q >> 3) & 7);
    offA[cc] = (c >> 3) * LDGA + (c & 7) * 8;
    offB[cc] = (c >> 3) * 1024 + (c & 7) * 8;
    dstc[cc] = base * 8;
  }
  const unsigned short* Abase = gA + (size_t)rb * 256 * LDGA + AOFF;
  const unsigned short* Bbase = gB + (size_t)cb * 256 * 1024;

#define SA(kt, half)                                                          \
  {                                                                           \
    _Pragma("unroll") for (int cc = 0; cc < 2; ++cc)                          \
        __builtin_amdgcn_global_load_lds(                                     \
            (gas1_t)(Abase + (size_t)(half) * 128 * LDGA + offA[cc] +         \
                     (kt) * ASTR),                                            \
            (las3_t)(lds + ((kt) & 1) * 16384 + (half) * 8192 + dstc[cc]),    \
            16, 0, 0);                                                        \
  }
#define SB(kt, half)                                                          \
  {                                                                           \
    _Pragma("unroll") for (int cc = 0; cc < 2; ++cc)                          \
        __builtin_amdgcn_global_load_lds(                                     \
            (gas1_t)(Bbase + (size_t)(half) * 128 * 1024 + offB[cc] +         \
                     (kt) * 64),                                              \
            (las3_t)(lds + 32768 + ((kt) & 1) * 16384 + (half) * 8192 +       \
                     dstc[cc]),                                               \
            16, 0, 0);                                                        \
  }

  f4v acc[8][4];
#pragma unroll
  for (int i = 0; i < 8; ++i)
#pragma unroll
    for (int j = 0; j < 4; ++j) acc[i][j] = (f4v){0.f, 0.f, 0.f, 0.f};

  // prologue: full tile 0 (A0,A1,B0,B1) + B halves of tile 1
  SA(0, 0); SA(0, 1); SB(0, 0); SB(0, 1); SB(1, 0); SB(1, 1);

  for (int kt = 0; kt < NT; ++kt) {
    // top-of-tile: all of tile kt landed; B halves of kt+1 may pend (4 loads)
    if (kt < NT - 1) {
      asm volatile("s_waitcnt vmcnt(4)" ::: "memory");
    } else {
      asm volatile("s_waitcnt vmcnt(0)" ::: "memory");
    }
    __builtin_amdgcn_sched_barrier(0);
    __builtin_amdgcn_s_barrier();
    const unsigned short* Ah = lds + (kt & 1) * 16384 + wr * 8192;
    const unsigned short* Bh =
        lds + 32768 + (kt & 1) * 16384 + (wc >> 1) * 8192;
    const int br0 = (wc & 1) * 64;

    // ---- ph0: read all B frags + A rf0-1; stage A0(kt+1) ----
    bh8 bfr[4][2], a0[2][2];
#pragma unroll
    for (int nf = 0; nf < 4; ++nf)
#pragma unroll
      for (int kf = 0; kf < 2; ++kf)
        bfr[nf][kf] = frag(Bh, br0 + nf * 16 + c0, kf * 4 + g4);
#pragma unroll
    for (int i = 0; i < 2; ++i)
#pragma unroll
      for (int kf = 0; kf < 2; ++kf)
        a0[i][kf] = frag(Ah, i * 16 + c0, kf * 4 + g4);
    if (kt + 1 < NT) SA(kt + 1, 0);
    __builtin_amdgcn_s_barrier();
    __builtin_amdgcn_s_setprio(1);
#pragma unroll
    for (int i = 0; i < 2; ++i)
#pragma unroll
      for (int nf = 0; nf < 4; ++nf)
#pragma unroll
        for (int kf = 0; kf < 2; ++kf)
          acc[i][nf] = mfma16(bfr[nf][kf], a0[i][kf], acc[i][nf]);
    __builtin_amdgcn_s_setprio(0);
    __builtin_amdgcn_s_barrier();

    // ---- ph1: read A rf2-3; stage A1(kt+1) ----
    bh8 a1[2][2];
#pragma unroll
    for (int i = 0; i < 2; ++i)
#pragma unroll
      for (int kf = 0; kf < 2; ++kf)
        a1[i][kf] = frag(Ah, (2 + i) * 16 + c0, kf * 4 + g4);
    if (kt + 1 < NT) SA(kt + 1, 1);
    __builtin_amdgcn_s_barrier();
    __builtin_amdgcn_s_setprio(1);
#pragma unroll
    for (int i = 0; i < 2; ++i)
#pragma unroll
      for (int nf = 0; nf < 4; ++nf)
#pragma unroll
        for (int kf = 0; kf < 2; ++kf)
          acc[2 + i][nf] = mfma16(bfr[nf][kf], a1[i][kf], acc[2 + i][nf]);
    __builtin_amdgcn_s_setprio(0);
    __builtin_amdgcn_s_barrier();

    // ---- ph2: read A rf4-5; stage B0(kt+2) ----
    bh8 a2[2][2];
#pragma unroll
    for (int i = 0; i < 2; ++i)
#pragma unroll
      for (int kf = 0; kf < 2; ++kf)
        a2[i][kf] = frag(Ah, (4 + i) * 16 + c0, kf * 4 + g4);
    if (kt + 2 < NT) SB(kt + 2, 0);
    __builtin_amdgcn_s_barrier();
    __builtin_amdgcn_s_setprio(1);
#pragma unroll
    for (int i = 0; i < 2; ++i)
#pragma unroll
      for (int nf = 0; nf < 4; ++nf)
#pragma unroll
        for (int kf = 0; kf < 2; ++kf)
          acc[4 + i][nf] = mfma16(bfr[nf][kf], a2[i][kf], acc[4 + i][nf]);
    __builtin_amdgcn_s_setprio(0);
    __builtin_amdgcn_s_barrier();

    // ---- ph3: read A rf6-7; stage B1(kt+2) ----
    bh8 a3[2][2];
#pragma unroll
    for (int i = 0; i < 2; ++i)
#pragma unroll
      for (int kf = 0; kf < 2; ++kf)
        a3[i][kf] = frag(Ah, (6 + i) * 16 + c0, kf * 4 + g4);
    if (kt + 2 < NT) SB(kt + 2, 1);
    __builtin_amdgcn_s_barrier();
    __builtin_amdgcn_s_setprio(1);
#pragma unroll
    for (int i = 0; i < 2; ++i)
#pragma unroll
      for (int nf = 0; nf < 4; ++nf)
#pragma unroll
        for (int kf = 0; kf < 2; ++kf)
          acc[6 + i][nf] = mfma16(bfr[nf][kf], a3[i][kf], acc[6 + i][nf]);
    __builtin_amdgcn_s_setprio(0);
    // no trailing barrier: top-of-tile vmcnt+barrier follows
  }
#undef SA
#undef SB

  // epilogue — swapped operands: lane holds row = c0 (16 rows/frag),
  // cols = nf*16 + g4*4 + r (4 consecutive) -> vector stores
  if (MODE == 0) {
    float bgv[4][4];
    if (wc == 3) {
#pragma unroll
      for (int nf = 0; nf < 4; ++nf) {
        const float4 bv =
            *reinterpret_cast<const float4*>(bg + cb * 64 + nf * 16 + g4 * 4);
        bgv[nf][0] = bv.x; bgv[nf][1] = bv.y;
        bgv[nf][2] = bv.z; bgv[nf][3] = bv.w;
      }
    }
#pragma unroll
    for (int rf = 0; rf < 8; ++rf) {
      const size_t row = (size_t)rb * 256 + wr * 128 + rf * 16 + c0;
#pragma unroll
      for (int nf = 0; nf < 4; ++nf) {
        ushort4 o;
#pragma unroll
        for (int r = 0; r < 4; ++r) {
          float v = acc[rf][nf][r];
          if (wc <= 1) v = elu1(v);                                   // q,k
          else if (wc == 3) v = 1.f / (1.f + __expf(-(v + bgv[nf][r])));  // g
          ((unsigned short*)&o)[r] = f2bf(v);
        }
        *reinterpret_cast<ushort4*>(
            ob + row * 4096 + cb * 256 + wc * 64 + nf * 16 + g4 * 4) = o;
      }
    }
  } else {
#pragma unroll
    for (int rf = 0; rf < 8; ++rf) {
      const size_t row = (size_t)rb * 256 + wr * 128 + rf * 16 + c0;
#pragma unroll
      for (int nf = 0; nf < 4; ++nf) {
        float4 o;
        o.x = acc[rf][nf][0]; o.y = acc[rf][nf][1];
        o.z = acc[rf][nf][2]; o.w = acc[rf][nf][3];
        *reinterpret_cast<float4*>(
            of + row * DIM + cb * 256 + wc * 64 + nf * 16 + g4 * 4) = o;
      }
    }
  }
}

// ---- G2: kv-state partials (fp32 outer product), 128 rows per block --------
__global__ __launch_bounds__(256) void g2(const unsigned short* __restrict__ qkvg,
                                          float* __restrict__ kv_part,
                                          float* __restrict__ ksum_part) {
  const int h = blockIdx.x, z = blockIdx.y;
  const int bb = z >> 5, sp = z & 31;
  const int t = threadIdx.x, ti = t >> 4, tj = t & 15;
  __shared__ unsigned short s[128 * 128];
  float kvacc[4][4] = {{0.f}};
  float ksacc[4] = {0.f, 0.f, 0.f, 0.f};
  const unsigned short* src =
      qkvg + ((size_t)bb * 4096 + sp * 128) * 4096 + h * 256 + 64;  // k|v
#pragma unroll
  for (int it = 0; it < 8; ++it) {
    const int idx = it * 256 + t;
    const int r = idx >> 4, c8 = idx & 15;
    *reinterpret_cast<bh8*>(&s[r * 128 + c8 * 8]) =
        *reinterpret_cast<const bh8*>(src + (size_t)r * 4096 + c8 * 8);
  }
  __syncthreads();
  for (int r = 0; r < 128; ++r) {
    const bh4 k4 = *reinterpret_cast<const bh4*>(&s[r * 128 + 4 * ti]);
    const bh4 v4 = *reinterpret_cast<const bh4*>(&s[r * 128 + 64 + 4 * tj]);
    float kf[4], vf[4];
#pragma unroll
    for (int i = 0; i < 4; ++i) {
      kf[i] = bf2f((unsigned short)k4[i]);
      vf[i] = bf2f((unsigned short)v4[i]);
      ksacc[i] += kf[i];
    }
#pragma unroll
    for (int i = 0; i < 4; ++i)
#pragma unroll
      for (int j = 0; j < 4; ++j) kvacc[i][j] = fmaf(kf[i], vf[j], kvacc[i][j]);
  }
  float* kp = kv_part + (((size_t)(bb * 16 + h)) * 32 + sp) * 4096;
#pragma unroll
  for (int i = 0; i < 4; ++i)
#pragma unroll
    for (int j = 0; j < 4; ++j) kp[(4 * ti + i) * 64 + 4 * tj + j] = kvacc[i][j];
  if (tj == 0) {
#pragma unroll
    for (int i = 0; i < 4; ++i)
      ksum_part[(((size_t)(bb * 16 + h)) * 32 + sp) * 64 + 4 * ti + i] = ksacc[i];
  }
}

// ---- G2r: reduce partials -> kvT bf16 [bh][e][d], ksum fp32 ----------------
__global__ __launch_bounds__(256) void g2r(const float* __restrict__ kv_part,
                                           const float* __restrict__ ksum_part,
                                           unsigned short* __restrict__ kvT,
                                           float* __restrict__ ksum, int b0) {
  const int bhl = blockIdx.x, t = threadIdx.x;
  const size_t bh = (size_t)b0 * 16 + bhl;
#pragma unroll
  for (int i = 0; i < 16; ++i) {
    const int idx = i * 256 + t;
    const int d = idx >> 6, e = idx & 63;
    float s = 0.f;
    for (int sp = 0; sp < 32; ++sp)
      s += kv_part[((size_t)bhl * 32 + sp) * 4096 + idx];
    kvT[bh * 4096 + e * 64 + d] = f2bf(s);
  }
  if (t < 64) {
    float s = 0.f;
    for (int sp = 0; sp < 32; ++sp)
      s += ksum_part[((size_t)bhl * 32 + sp) * 64 + t];
    ksum[bh * 64 + t] = s;
  }
}

// ---- G3: attn apply: o = q@kv * z * g -> bf16 into k-slot of qkvg ----------
__global__ __launch_bounds__(256) void g3(unsigned short* __restrict__ qkvg,
                                          const unsigned short* __restrict__ kvT,
                                          const float* __restrict__ ksum,
                                          int b0) {
  const int h = blockIdx.x, z = blockIdx.y;
  const int t = threadIdx.x, lane = t & 63, w = t >> 6;
  const int g4 = lane >> 4, c0 = lane & 15;
  __shared__ unsigned short sQ[8192];
  __shared__ unsigned short skv[64 * 72];
  __shared__ float sks[64], sden[128];
  const int bb = z >> 5;
  const size_t bh = (size_t)(b0 + bb) * 16 + h;
  for (int i = t; i < 4096; i += 256)
    skv[(i >> 6) * 72 + (i & 63)] = kvT[bh * 4096 + i];
  if (t < 64) sks[t] = ksum[bh * 64 + t];
  const size_t row0 = (size_t)z * 128;
  gll_tile(qkvg + row0 * 4096 + h * 256, 4096, sQ, t);
  __syncthreads();
  if (t < 128) {
    float s = 0.f;
    for (int d = 0; d < 64; ++d)
      s += bf2f(sQ[((((t) << 3) | (d >> 3)) ^ (t & 7)) * 8 + (d & 7)]) * sks[d];
    sden[t] = SCALE / fmaxf(s, 1e-6f);
  }
  __syncthreads();
  f4v oacc[2][4];
#pragma unroll
  for (int ii = 0; ii < 2; ++ii)
#pragma unroll
    for (int et = 0; et < 4; ++et) oacc[ii][et] = (f4v){0.f, 0.f, 0.f, 0.f};
#pragma unroll
  for (int kf = 0; kf < 2; ++kf) {
    bh8 aq[2];
#pragma unroll
    for (int ii = 0; ii < 2; ++ii)
      aq[ii] = frag(sQ, w * 32 + ii * 16 + c0, kf * 4 + g4);
#pragma unroll
    for (int et = 0; et < 4; ++et) {
      const bh8 bkv = *reinterpret_cast<const bh8*>(
          skv + (et * 16 + c0) * 72 + kf * 32 + g4 * 8);
#pragma unroll
      for (int ii = 0; ii < 2; ++ii)
        oacc[ii][et] = mfma16(aq[ii], bkv, oacc[ii][et]);
    }
  }
#pragma unroll
  for (int ii = 0; ii < 2; ++ii)
#pragma unroll
    for (int et = 0; et < 4; ++et)
#pragma unroll
      for (int r = 0; r < 4; ++r) {
        const int row = w * 32 + ii * 16 + g4 * 4 + r;
        const int e = et * 16 + c0;
        const float gv = bf2f(qkvg[(row0 + row) * 4096 + h * 256 + 192 + e]);
        qkvg[(row0 + row) * 4096 + h * 256 + 64 + e] =
            f2bf(oacc[ii][et][r] * sden[row] * gv);
      }
}

// ---------------------------------------------------------------------------
extern "C" void kernel_launch(void* const* d_in, const int* in_sizes, int n_in,
                              void* d_out, int out_size, void* d_ws,
                              size_t ws_size, hipStream_t stream) {
  const float* x  = (const float*)d_in[0];
  const float* Wq = (const float*)d_in[1];
  const float* Wk = (const float*)d_in[2];
  const float* Wv = (const float*)d_in[3];
  const float* Wg = (const float*)d_in[4];
  const float* bg = (const float*)d_in[5];
  const float* Wo = (const float*)d_in[6];
  float* out = (float*)d_out;
  char* w = (char*)d_ws;

  int nbat = 1;
  if (ws_size >= 11026432ull + 4ull * 50462720ull) nbat = 4;
  else if (ws_size >= 11026432ull + 2ull * 50462720ull) nbat = 2;

  unsigned short* WallT = (unsigned short*)(w);                  // 8 MiB
  unsigned short* WoT   = (unsigned short*)(w + 8388608);        // 2 MiB
  unsigned short* kvT   = (unsigned short*)(w + 10485760);       // 512 KiB
  float*          ksum  = (float*)(w + 11010048);                // 16 KiB
  char* dyn = w + 11026432;
  float* kv_part        = (float*)dyn;
  float* ksum_part      = (float*)(dyn + (size_t)nbat * 8388608);
  unsigned short* xb    = (unsigned short*)(dyn + (size_t)nbat * (8388608 + 131072));
  unsigned short* qkvg  = (unsigned short*)(dyn + (size_t)nbat * (8388608 + 131072 + 8388608));

  p1<<<dim3(16, 16, 5), 256, 0, stream>>>(Wq, Wk, Wv, Wg, Wo, WallT, WoT);

  for (int b0 = 0; b0 < 4; b0 += nbat) {
    const int rows_p = nbat * 4096;
    p0<<<rows_p / 2, 256, 0, stream>>>(x + (size_t)b0 * 4096 * DIM, xb);
    gemm8<0><<<dim3((rows_p / 256) * 16), 512, 0, stream>>>(xb, WallT, bg,
                                                            qkvg, nullptr);
    g2<<<dim3(16, nbat * 32), 256, 0, stream>>>(qkvg, kv_part, ksum_part);
    g2r<<<nbat * 16, 256, 0, stream>>>(kv_part, ksum_part, kvT, ksum, b0);
    g3<<<dim3(16, nbat * 32), 256, 0, stream>>>(qkvg, kvT, ksum, b0);
    gemm8<1><<<dim3((rows_p / 256) * 4), 512, 0, stream>>>(
        qkvg, WoT, nullptr, nullptr, out + (size_t)b0 * 4096 * DIM);
  }
}

// Round 5
// 312.129 us; speedup vs baseline: 7.2949x; 1.0659x over previous
//
#include <hip/hip_runtime.h>
#include <math.h>

#define DIM 1024
#define SCALE 0.125f
#define NT 16  // K-tiles of 64

typedef __attribute__((ext_vector_type(8))) short bh8;
typedef __attribute__((ext_vector_type(4))) short bh4;
typedef __attribute__((ext_vector_type(4))) float f4v;

__device__ __forceinline__ unsigned short f2bf(float f) {
  unsigned u = __builtin_bit_cast(unsigned, f);
  return (unsigned short)((u + 0x7FFFu + ((u >> 16) & 1u)) >> 16);
}
__device__ __forceinline__ float bf2f(unsigned short u) {
  return __builtin_bit_cast(float, (unsigned)u << 16);
}
__device__ __forceinline__ float elu1(float v) {
  return v > 0.f ? v + 1.f : __expf(v);
}
__device__ __forceinline__ f4v mfma16(bh8 a, bh8 b, f4v c) {
  return __builtin_amdgcn_mfma_f32_16x16x32_bf16(a, b, c, 0, 0, 0);
}

typedef const void __attribute__((address_space(1)))* gas1_t;
typedef void __attribute__((address_space(3)))* las3_t;

// 128x64 bf16 half-tile in LDS as 1024 16B chunks, swizzle q = c ^ ((c>>3)&7)
__device__ __forceinline__ bh8 frag(const unsigned short* lds, int row, int k8) {
  const int q = ((row << 3) | k8) ^ (row & 7);
  return *reinterpret_cast<const bh8*>(lds + q * 8);
}

// 256-thread staging helper (used by g3): 128x64 tile, 4 chunks/thread
__device__ __forceinline__ void gll_tile(const unsigned short* g, int ldg,
                                         unsigned short* lds, int t) {
  const int lane = t & 63, w = t >> 6;
#pragma unroll
  for (int cc = 0; cc < 4; ++cc) {
    const int base = (w * 4 + cc) * 64;
    const int q = base + lane;
    const int c = q ^ ((q >> 3) & 7);
    __builtin_amdgcn_global_load_lds(
        (gas1_t)(const void*)(g + (size_t)(c >> 3) * ldg + (c & 7) * 8),
        (las3_t)(void*)(lds + (size_t)base * 8), 16, 0, 0);
  }
}

// ---- P0: x fp32 -> bf16 ----------------------------------------------------
__global__ __launch_bounds__(256) void p0(const float* __restrict__ x,
                                          unsigned short* __restrict__ xb) {
  const size_t i = ((size_t)blockIdx.x * 256 + threadIdx.x) * 8;
  const float4 a = *reinterpret_cast<const float4*>(x + i);
  const float4 b = *reinterpret_cast<const float4*>(x + i + 4);
  bh8 v;
  v[0] = (short)f2bf(a.x); v[1] = (short)f2bf(a.y);
  v[2] = (short)f2bf(a.z); v[3] = (short)f2bf(a.w);
  v[4] = (short)f2bf(b.x); v[5] = (short)f2bf(b.y);
  v[6] = (short)f2bf(b.z); v[7] = (short)f2bf(b.w);
  *reinterpret_cast<bh8*>(xb + i) = v;
}

// ---- P1: weights fp32 -> bf16 transposed -----------------------------------
__global__ __launch_bounds__(256) void p1(
    const float* __restrict__ Wq, const float* __restrict__ Wk,
    const float* __restrict__ Wv, const float* __restrict__ Wg,
    const float* __restrict__ Wo, unsigned short* __restrict__ WallT,
    unsigned short* __restrict__ WoT) {
  const int m = blockIdx.z;
  const int tc = blockIdx.x, tr = blockIdx.y;
  const int t = threadIdx.x;
  const float* src = m == 0 ? Wq : m == 1 ? Wk : m == 2 ? Wv : m == 3 ? Wg : Wo;
  __shared__ float tile[64][65];
#pragma unroll
  for (int i = 0; i < 4; ++i) {
    const int idx = i * 256 + t;
    const int r = idx >> 4;
    const int c4 = (idx & 15) * 4;
    const float4 v = *reinterpret_cast<const float4*>(
        src + (size_t)(tr * 64 + r) * DIM + tc * 64 + c4);
    tile[r][c4] = v.x; tile[r][c4 + 1] = v.y;
    tile[r][c4 + 2] = v.z; tile[r][c4 + 3] = v.w;
  }
  __syncthreads();
  unsigned short* dst = (m < 4) ? WallT : WoT;
#pragma unroll
  for (int i = 0; i < 4; ++i) {
    const int idx = i * 256 + t;
    const int lc = idx >> 4;
    const int k4i = (idx & 15) * 4;
    const size_t drow = (m < 4) ? (size_t)(tc * 256 + m * 64 + lc)
                                : (size_t)(tc * 64 + lc);
    bh4 v;
#pragma unroll
    for (int jj = 0; jj < 4; ++jj) v[jj] = (short)f2bf(tile[k4i + jj][lc]);
    *reinterpret_cast<bh4*>(dst + drow * DIM + tr * 64 + k4i) = v;
  }
}

// ---- gemm8: 256x256 tile, 8-phase counted-vmcnt pipeline --------------------
// MODE 0: qkvg = xb @ WallT^T, fused activations, bf16 out (4096 cols)
// MODE 1: out = attn(k-slot of qkvg) @ WoT^T, f32 out (1024 cols)
template <int MODE>
__global__ __launch_bounds__(512, 2) void gemm8(
    const unsigned short* __restrict__ gA,
    const unsigned short* __restrict__ gB, const float* __restrict__ bg,
    unsigned short* __restrict__ ob, float* __restrict__ of) {
  const int t = threadIdx.x, lane = t & 63, w = t >> 6;
  const int wr = w >> 2, wc = w & 3, g4 = lane >> 4, c0 = lane & 15;
  const int nwg = gridDim.x;
  const int NBC = (MODE == 0) ? 16 : 4;
  const int rbn = nwg / NBC;
  // XCD row-band swizzle: XCD x owns rb in [x*bandsz, (x+1)*bandsz), cb-major
  // within the band so the A-band (bandsz*256 rows) stays L2-resident.
  const int bid = (int)blockIdx.x;
  const int xcd = bid & 7;
  const int idx = bid >> 3;
  const int bandsz = rbn >> 3;  // = 8 for both modes
  const int cb = idx / bandsz;
  const int rb = xcd * bandsz + (idx - cb * bandsz);

  constexpr int LDGA = (MODE == 0) ? 1024 : 4096;
  constexpr int ASTR = (MODE == 0) ? 64 : 256;
  constexpr int AOFF = (MODE == 0) ? 0 : 64;

  __shared__ __align__(16) unsigned short lds[65536];  // 128 KiB

  // per-thread chunk offsets (2 chunks per half-tile stage)
  int offA[2], offB[2], dstc[2];
#pragma unroll
  for (int cc = 0; cc < 2; ++cc) {
    const int base = (w * 2 + cc) * 64;
    const int q = base + lane;
    const int c = q ^ ((q >> 3) & 7);
    offA[cc] = (c >> 3) * LDGA + (c & 7) * 8;
    offB[cc] = (c >> 3) * 1024 + (c & 7) * 8;
    dstc[cc] = base * 8;
  }
  const unsigned short* Abase = gA + (size_t)rb * 256 * LDGA + AOFF;
  const unsigned short* Bbase = gB + (size_t)cb * 256 * 1024;

#define SA(kt, half)                                                          \
  {                                                                           \
    _Pragma("unroll") for (int cc = 0; cc < 2; ++cc)                          \
        __builtin_amdgcn_global_load_lds(                                     \
            (gas1_t)(Abase + (size_t)(half) * 128 * LDGA + offA[cc] +         \
                     (kt) * ASTR),                                            \
            (las3_t)(lds + ((kt) & 1) * 16384 + (half) * 8192 + dstc[cc]),    \
            16, 0, 0);                                                        \
  }
#define SB(kt, half)                                                          \
  {                                                                           \
    _Pragma("unroll") for (int cc = 0; cc < 2; ++cc)                          \
        __builtin_amdgcn_global_load_lds(                                     \
            (gas1_t)(Bbase + (size_t)(half) * 128 * 1024 + offB[cc] +         \
                     (kt) * 64),                                              \
            (las3_t)(lds + 32768 + ((kt) & 1) * 16384 + (half) * 8192 +       \
                     dstc[cc]),                                               \
            16, 0, 0);                                                        \
  }

  f4v acc[8][4];
#pragma unroll
  for (int i = 0; i < 8; ++i)
#pragma unroll
    for (int j = 0; j < 4; ++j) acc[i][j] = (f4v){0.f, 0.f, 0.f, 0.f};

  // prologue: B(0), A(0) (awaited at tile 0), then B(1) halves (in flight)
  SB(0, 0); SB(0, 1); SA(0, 0); SA(0, 1); SB(1, 0); SB(1, 1);

#pragma unroll 2
  for (int kt = 0; kt < NT; ++kt) {
    // top-of-tile: all of tile kt landed; B halves of kt+1 may pend (4 loads)
    if (kt < NT - 1) {
      asm volatile("s_waitcnt vmcnt(4)" ::: "memory");
    } else {
      asm volatile("s_waitcnt vmcnt(0)" ::: "memory");
    }
    __builtin_amdgcn_sched_barrier(0);
    __builtin_amdgcn_s_barrier();
    const unsigned short* Ah = lds + (kt & 1) * 16384 + wr * 8192;
    const unsigned short* Bh =
        lds + 32768 + (kt & 1) * 16384 + (wc >> 1) * 8192;
    const int br0 = (wc & 1) * 64;

    // ---- ph0: read all B frags + A rf0-1; stage A0,A1(kt+1) ----
    bh8 bfr[4][2], a0[2][2];
#pragma unroll
    for (int nf = 0; nf < 4; ++nf)
#pragma unroll
      for (int kf = 0; kf < 2; ++kf)
        bfr[nf][kf] = frag(Bh, br0 + nf * 16 + c0, kf * 4 + g4);
#pragma unroll
    for (int i = 0; i < 2; ++i)
#pragma unroll
      for (int kf = 0; kf < 2; ++kf)
        a0[i][kf] = frag(Ah, i * 16 + c0, kf * 4 + g4);
    if (kt + 1 < NT) { SA(kt + 1, 0); SA(kt + 1, 1); }
    __builtin_amdgcn_s_barrier();
    __builtin_amdgcn_s_setprio(1);
#pragma unroll
    for (int i = 0; i < 2; ++i)
#pragma unroll
      for (int nf = 0; nf < 4; ++nf)
#pragma unroll
        for (int kf = 0; kf < 2; ++kf)
          acc[i][nf] = mfma16(bfr[nf][kf], a0[i][kf], acc[i][nf]);
    __builtin_amdgcn_s_setprio(0);
    __builtin_amdgcn_s_barrier();

    // ---- ph1: read A rf2-3; stage B0(kt+2) ----
    bh8 a1[2][2];
#pragma unroll
    for (int i = 0; i < 2; ++i)
#pragma unroll
      for (int kf = 0; kf < 2; ++kf)
        a1[i][kf] = frag(Ah, (2 + i) * 16 + c0, kf * 4 + g4);
    if (kt + 2 < NT) SB(kt + 2, 0);
    __builtin_amdgcn_s_barrier();
    __builtin_amdgcn_s_setprio(1);
#pragma unroll
    for (int i = 0; i < 2; ++i)
#pragma unroll
      for (int nf = 0; nf < 4; ++nf)
#pragma unroll
        for (int kf = 0; kf < 2; ++kf)
          acc[2 + i][nf] = mfma16(bfr[nf][kf], a1[i][kf], acc[2 + i][nf]);
    __builtin_amdgcn_s_setprio(0);
    __builtin_amdgcn_s_barrier();

    // ---- ph2: read A rf4-5; stage B1(kt+2) ----
    bh8 a2[2][2];
#pragma unroll
    for (int i = 0; i < 2; ++i)
#pragma unroll
      for (int kf = 0; kf < 2; ++kf)
        a2[i][kf] = frag(Ah, (4 + i) * 16 + c0, kf * 4 + g4);
    if (kt + 2 < NT) SB(kt + 2, 1);
    __builtin_amdgcn_s_barrier();
    __builtin_amdgcn_s_setprio(1);
#pragma unroll
    for (int i = 0; i < 2; ++i)
#pragma unroll
      for (int nf = 0; nf < 4; ++nf)
#pragma unroll
        for (int kf = 0; kf < 2; ++kf)
          acc[4 + i][nf] = mfma16(bfr[nf][kf], a2[i][kf], acc[4 + i][nf]);
    __builtin_amdgcn_s_setprio(0);
    __builtin_amdgcn_s_barrier();

    // ---- ph3: read A rf6-7 ----
    bh8 a3[2][2];
#pragma unroll
    for (int i = 0; i < 2; ++i)
#pragma unroll
      for (int kf = 0; kf < 2; ++kf)
        a3[i][kf] = frag(Ah, (6 + i) * 16 + c0, kf * 4 + g4);
    __builtin_amdgcn_s_barrier();
    __builtin_amdgcn_s_setprio(1);
#pragma unroll
    for (int i = 0; i < 2; ++i)
#pragma unroll
      for (int nf = 0; nf < 4; ++nf)
#pragma unroll
        for (int kf = 0; kf < 2; ++kf)
          acc[6 + i][nf] = mfma16(bfr[nf][kf], a3[i][kf], acc[6 + i][nf]);
    __builtin_amdgcn_s_setprio(0);
    // no trailing barrier: top-of-tile vmcnt+barrier follows
  }
#undef SA
#undef SB

  // epilogue — swapped operands: lane holds row = c0 (16 rows/frag),
  // cols = nf*16 + g4*4 + r (4 consecutive) -> vector stores
  if (MODE == 0) {
    float bgv[4][4];
    if (wc == 3) {
#pragma unroll
      for (int nf = 0; nf < 4; ++nf) {
        const float4 bv =
            *reinterpret_cast<const float4*>(bg + cb * 64 + nf * 16 + g4 * 4);
        bgv[nf][0] = bv.x; bgv[nf][1] = bv.y;
        bgv[nf][2] = bv.z; bgv[nf][3] = bv.w;
      }
    }
#pragma unroll
    for (int rf = 0; rf < 8; ++rf) {
      const size_t row = (size_t)rb * 256 + wr * 128 + rf * 16 + c0;
#pragma unroll
      for (int nf = 0; nf < 4; ++nf) {
        ushort4 o;
#pragma unroll
        for (int r = 0; r < 4; ++r) {
          float v = acc[rf][nf][r];
          if (wc <= 1) v = elu1(v);                                   // q,k
          else if (wc == 3) v = 1.f / (1.f + __expf(-(v + bgv[nf][r])));  // g
          ((unsigned short*)&o)[r] = f2bf(v);
        }
        *reinterpret_cast<ushort4*>(
            ob + row * 4096 + cb * 256 + wc * 64 + nf * 16 + g4 * 4) = o;
      }
    }
  } else {
#pragma unroll
    for (int rf = 0; rf < 8; ++rf) {
      const size_t row = (size_t)rb * 256 + wr * 128 + rf * 16 + c0;
#pragma unroll
      for (int nf = 0; nf < 4; ++nf) {
        float4 o;
        o.x = acc[rf][nf][0]; o.y = acc[rf][nf][1];
        o.z = acc[rf][nf][2]; o.w = acc[rf][nf][3];
        *reinterpret_cast<float4*>(
            of + row * DIM + cb * 256 + wc * 64 + nf * 16 + g4 * 4) = o;
      }
    }
  }
}

// ---- G2: kv-state partials (fp32 outer product), 128 rows per block --------
__global__ __launch_bounds__(256) void g2(const unsigned short* __restrict__ qkvg,
                                          float* __restrict__ kv_part,
                                          float* __restrict__ ksum_part) {
  const int h = blockIdx.x, z = blockIdx.y;
  const int bb = z >> 5, sp = z & 31;
  const int t = threadIdx.x, ti = t >> 4, tj = t & 15;
  __shared__ unsigned short s[128 * 128];
  float kvacc[4][4] = {{0.f}};
  float ksacc[4] = {0.f, 0.f, 0.f, 0.f};
  const unsigned short* src =
      qkvg + ((size_t)bb * 4096 + sp * 128) * 4096 + h * 256 + 64;  // k|v
#pragma unroll
  for (int it = 0; it < 8; ++it) {
    const int idx = it * 256 + t;
    const int r = idx >> 4, c8 = idx & 15;
    *reinterpret_cast<bh8*>(&s[r * 128 + c8 * 8]) =
        *reinterpret_cast<const bh8*>(src + (size_t)r * 4096 + c8 * 8);
  }
  __syncthreads();
  for (int r = 0; r < 128; ++r) {
    const bh4 k4 = *reinterpret_cast<const bh4*>(&s[r * 128 + 4 * ti]);
    const bh4 v4 = *reinterpret_cast<const bh4*>(&s[r * 128 + 64 + 4 * tj]);
    float kf[4], vf[4];
#pragma unroll
    for (int i = 0; i < 4; ++i) {
      kf[i] = bf2f((unsigned short)k4[i]);
      vf[i] = bf2f((unsigned short)v4[i]);
      ksacc[i] += kf[i];
    }
#pragma unroll
    for (int i = 0; i < 4; ++i)
#pragma unroll
      for (int j = 0; j < 4; ++j) kvacc[i][j] = fmaf(kf[i], vf[j], kvacc[i][j]);
  }
  float* kp = kv_part + (((size_t)(bb * 16 + h)) * 32 + sp) * 4096;
#pragma unroll
  for (int i = 0; i < 4; ++i)
#pragma unroll
    for (int j = 0; j < 4; ++j) kp[(4 * ti + i) * 64 + 4 * tj + j] = kvacc[i][j];
  if (tj == 0) {
#pragma unroll
    for (int i = 0; i < 4; ++i)
      ksum_part[(((size_t)(bb * 16 + h)) * 32 + sp) * 64 + 4 * ti + i] = ksacc[i];
  }
}

// ---- G2r: reduce partials -> kvT bf16 [bh][e][d], ksum fp32 ----------------
__global__ __launch_bounds__(256) void g2r(const float* __restrict__ kv_part,
                                           const float* __restrict__ ksum_part,
                                           unsigned short* __restrict__ kvT,
                                           float* __restrict__ ksum, int b0) {
  const int bhl = blockIdx.x, t = threadIdx.x;
  const size_t bh = (size_t)b0 * 16 + bhl;
#pragma unroll
  for (int i = 0; i < 16; ++i) {
    const int idx = i * 256 + t;
    const int d = idx >> 6, e = idx & 63;
    float s = 0.f;
    for (int sp = 0; sp < 32; ++sp)
      s += kv_part[((size_t)bhl * 32 + sp) * 4096 + idx];
    kvT[bh * 4096 + e * 64 + d] = f2bf(s);
  }
  if (t < 64) {
    float s = 0.f;
    for (int sp = 0; sp < 32; ++sp)
      s += ksum_part[((size_t)bhl * 32 + sp) * 64 + t];
    ksum[bh * 64 + t] = s;
  }
}

// ---- G3: attn apply: o = q@kv * z * g -> bf16 into k-slot of qkvg ----------
__global__ __launch_bounds__(256) void g3(unsigned short* __restrict__ qkvg,
                                          const unsigned short* __restrict__ kvT,
                                          const float* __restrict__ ksum,
                                          int b0) {
  const int h = blockIdx.x, z = blockIdx.y;
  const int t = threadIdx.x, lane = t & 63, w = t >> 6;
  const int g4 = lane >> 4, c0 = lane & 15;
  __shared__ unsigned short sQ[8192];
  __shared__ unsigned short skv[64 * 72];
  __shared__ float sks[64], sden[128];
  const int bb = z >> 5;
  const size_t bh = (size_t)(b0 + bb) * 16 + h;
  for (int i = t; i < 4096; i += 256)
    skv[(i >> 6) * 72 + (i & 63)] = kvT[bh * 4096 + i];
  if (t < 64) sks[t] = ksum[bh * 64 + t];
  const size_t row0 = (size_t)z * 128;
  gll_tile(qkvg + row0 * 4096 + h * 256, 4096, sQ, t);
  __syncthreads();
  if (t < 128) {
    float s = 0.f;
    for (int d = 0; d < 64; ++d)
      s += bf2f(sQ[((((t) << 3) | (d >> 3)) ^ (t & 7)) * 8 + (d & 7)]) * sks[d];
    sden[t] = SCALE / fmaxf(s, 1e-6f);
  }
  __syncthreads();
  f4v oacc[2][4];
#pragma unroll
  for (int ii = 0; ii < 2; ++ii)
#pragma unroll
    for (int et = 0; et < 4; ++et) oacc[ii][et] = (f4v){0.f, 0.f, 0.f, 0.f};
#pragma unroll
  for (int kf = 0; kf < 2; ++kf) {
    bh8 aq[2];
#pragma unroll
    for (int ii = 0; ii < 2; ++ii)
      aq[ii] = frag(sQ, w * 32 + ii * 16 + c0, kf * 4 + g4);
#pragma unroll
    for (int et = 0; et < 4; ++et) {
      const bh8 bkv = *reinterpret_cast<const bh8*>(
          skv + (et * 16 + c0) * 72 + kf * 32 + g4 * 8);
#pragma unroll
      for (int ii = 0; ii < 2; ++ii)
        oacc[ii][et] = mfma16(aq[ii], bkv, oacc[ii][et]);
    }
  }
#pragma unroll
  for (int ii = 0; ii < 2; ++ii)
#pragma unroll
    for (int et = 0; et < 4; ++et)
#pragma unroll
      for (int r = 0; r < 4; ++r) {
        const int row = w * 32 + ii * 16 + g4 * 4 + r;
        const int e = et * 16 + c0;
        const float gv = bf2f(qkvg[(row0 + row) * 4096 + h * 256 + 192 + e]);
        qkvg[(row0 + row) * 4096 + h * 256 + 64 + e] =
            f2bf(oacc[ii][et][r] * sden[row] * gv);
      }
}

// ---------------------------------------------------------------------------
extern "C" void kernel_launch(void* const* d_in, const int* in_sizes, int n_in,
                              void* d_out, int out_size, void* d_ws,
                              size_t ws_size, hipStream_t stream) {
  const float* x  = (const float*)d_in[0];
  const float* Wq = (const float*)d_in[1];
  const float* Wk = (const float*)d_in[2];
  const float* Wv = (const float*)d_in[3];
  const float* Wg = (const float*)d_in[4];
  const float* bg = (const float*)d_in[5];
  const float* Wo = (const float*)d_in[6];
  float* out = (float*)d_out;
  char* w = (char*)d_ws;

  int nbat = 1;
  if (ws_size >= 11026432ull + 4ull * 50462720ull) nbat = 4;
  else if (ws_size >= 11026432ull + 2ull * 50462720ull) nbat = 2;

  unsigned short* WallT = (unsigned short*)(w);                  // 8 MiB
  unsigned short* WoT   = (unsigned short*)(w + 8388608);        // 2 MiB
  unsigned short* kvT   = (unsigned short*)(w + 10485760);       // 512 KiB
  float*          ksum  = (float*)(w + 11010048);                // 16 KiB
  char* dyn = w + 11026432;
  float* kv_part        = (float*)dyn;
  float* ksum_part      = (float*)(dyn + (size_t)nbat * 8388608);
  unsigned short* xb    = (unsigned short*)(dyn + (size_t)nbat * (8388608 + 131072));
  unsigned short* qkvg  = (unsigned short*)(dyn + (size_t)nbat * (8388608 + 131072 + 8388608));

  p1<<<dim3(16, 16, 5), 256, 0, stream>>>(Wq, Wk, Wv, Wg, Wo, WallT, WoT);

  for (int b0 = 0; b0 < 4; b0 += nbat) {
    const int rows_p = nbat * 4096;
    p0<<<rows_p / 2, 256, 0, stream>>>(x + (size_t)b0 * 4096 * DIM, xb);
    gemm8<0><<<dim3((rows_p / 256) * 16), 512, 0, stream>>>(xb, WallT, bg,
                                                            qkvg, nullptr);
    g2<<<dim3(16, nbat * 32), 256, 0, stream>>>(qkvg, kv_part, ksum_part);
    g2r<<<nbat * 16, 256, 0, stream>>>(kv_part, ksum_part, kvT, ksum, b0);
    g3<<<dim3(16, nbat * 32), 256, 0, stream>>>(qkvg, kvT, ksum, b0);
    gemm8<1><<<dim3((rows_p / 256) * 4), 512, 0, stream>>>(
        qkvg, WoT, nullptr, nullptr, out + (size_t)b0 * 4096 * DIM);
  }
}